// Round 1
// baseline (1621.576 us; speedup 1.0000x reference)
//
#include <hip/hip_runtime.h>
#include <hip/hip_bf16.h>
#include <hip/hip_cooperative_groups.h>
#include <math.h>

namespace cg = cooperative_groups;

// ---------------------------------------------------------------------------
// Problem constants
// ---------------------------------------------------------------------------
namespace {
constexpr int BROWS = 8192;
constexpr int NLAB  = 4096;
constexpr int NUNL  = 4096;
constexpr int CREAL = 100;
constexpr int CPAD  = 112;    // 7 mfma col-tiles of 16
constexpr int DIM   = 512;
constexpr int MAXIT = 30;

constexpr size_t MiB = 1ull << 20;
// ws layout (bytes).  Peak live ~104.1 MiB; budget proven ~138 MiB.
constexpr size_t OFF_S    = 0;              // ushort[4096][8192] raw S  64 MiB (dead after it0)
constexpr size_t OFF_AU   = 64 * MiB;       // ushort[4096][4096] thresholded A (fallback path only)
constexpr size_t OFF_EB   = 96 * MiB;       // ushort[8192][512] emb bf16 (dead after simM) 8 MiB
// overlay of EB after simM:
constexpr size_t OFF_XT0  = 96 * MiB;       // ushort[112][8192] X^T ping 1.75 MiB
constexpr size_t OFF_XT1  = 98 * MiB;       // X^T pong
constexpr size_t OFF_XU   = 100 * MiB;      // float[4096][112] exact X (fallback only)
constexpr size_t OFF_PL   = 102 * MiB;      // float[4096][112] P_lab (fallback only)
// tail (never overlaid):
constexpr size_t OFF_HIST = 104 * MiB;          // float[4096]
constexpr size_t OFF_ERR  = 104 * MiB + 16384;  // float[32]
constexpr size_t OFF_MS   = 104 * MiB + 16768;  // double
constexpr size_t OFF_RN   = 104 * MiB + 32768;  // float[8192]
constexpr size_t MEMSET_LEN = 20480;            // HIST..MS inclusive

// cooperative k_loop dynamic LDS: AuL 131072 + part 28928 + dsqbuf 32
constexpr unsigned DLDS = 131072u + 28928u + 32u;   // 160032 <= 163840
}

typedef __attribute__((ext_vector_type(8))) short short8;
typedef __attribute__((ext_vector_type(4))) float floatx4;

__device__ inline ushort f2bf(float f) {
  __hip_bfloat16 h = __float2bfloat16(f);
  union { __hip_bfloat16 b; ushort u; } c; c.b = h; return c.u;
}
__device__ inline float bf2f(ushort u) {
  union { ushort u; __hip_bfloat16 b; } c; c.u = u;
  return __bfloat162float(c.b);
}

// ---------------------------------------------------------------------------
// Fused: row 1/norm + emb fp32 -> bf16 cast.  One block per row, 64 lanes.
// ---------------------------------------------------------------------------
__global__ __launch_bounds__(64) void k_prep(const float* __restrict__ emb,
                                             ushort* __restrict__ Eb,
                                             float* __restrict__ rn) {
  int row = blockIdx.x, l = threadIdx.x;
  const float4* e4 = (const float4*)(emb + (size_t)row * DIM);
  float4 a = e4[2 * l], b = e4[2 * l + 1];
  float f[8] = {a.x, a.y, a.z, a.w, b.x, b.y, b.z, b.w};
  float s = 0.f;
#pragma unroll
  for (int q = 0; q < 8; q++) s += f[q] * f[q];
#pragma unroll
  for (int m = 1; m < 64; m <<= 1) s += __shfl_xor(s, m);
  if (l == 0) rn[row] = 1.0f / fmaxf(sqrtf(s), 1e-12f);
  union { short8 v; ushort u[8]; } o;
#pragma unroll
  for (int q = 0; q < 8; q++) o.u[q] = f2bf(f[q]);
  *(short8*)(Eb + (size_t)row * DIM + l * 8) = o.v;
}

// ---------------------------------------------------------------------------
// X init (FALLBACK path only)
// ---------------------------------------------------------------------------
__global__ __launch_bounds__(256) void k_initX(ushort* __restrict__ X0,
                                               ushort* __restrict__ X1,
                                               float* __restrict__ Xu,
                                               const int* __restrict__ labels) {
  int j = blockIdx.x * 256 + threadIdx.x;       // 0..8191
  int c = blockIdx.y;                            // 0..111
  float v;
  if (j < NLAB) v = (labels[j] == c) ? 1.0f : 0.0f;
  else          v = (c < CREAL) ? 0.01f : 0.0f;
  ushort b = f2bf(v);
  X0[(size_t)c * BROWS + j] = b;
  X1[(size_t)c * BROWS + j] = b;
  if (j >= NLAB) Xu[(size_t)(j - NLAB) * CPAD + c] = (c < CREAL) ? 0.01f : 0.0f;
}

// ---------------------------------------------------------------------------
// MLP 512->256->128->64->1 (verified)
// ---------------------------------------------------------------------------
__global__ __launch_bounds__(256) void k_mlp(const float* __restrict__ emb,
                                             const float* __restrict__ W1, const float* __restrict__ b1,
                                             const float* __restrict__ W2, const float* __restrict__ b2,
                                             const float* __restrict__ W3, const float* __restrict__ b3,
                                             const float* __restrict__ Wc, const float* __restrict__ bc,
                                             float* __restrict__ out) {
  __shared__ float xs[4][512];
  __shared__ float h1[4][256];
  __shared__ float h2[4][128];
  __shared__ float h3[4][64];
  int t = threadIdx.x;
  int r0 = blockIdx.x * 4;
  {
    const float4* src = (const float4*)(emb + (size_t)r0 * DIM);
    float4* dst = (float4*)&xs[0][0];
    dst[t] = src[t];
    dst[t + 256] = src[t + 256];
  }
  __syncthreads();
  {
    float a0 = 0.f, a1 = 0.f, a2 = 0.f, a3 = 0.f;
    for (int k = 0; k < 512; k++) {
      float w = W1[k * 256 + t];
      a0 = fmaf(xs[0][k], w, a0);
      a1 = fmaf(xs[1][k], w, a1);
      a2 = fmaf(xs[2][k], w, a2);
      a3 = fmaf(xs[3][k], w, a3);
    }
    float bb = b1[t];
    h1[0][t] = fmaxf(a0 + bb, 0.f);
    h1[1][t] = fmaxf(a1 + bb, 0.f);
    h1[2][t] = fmaxf(a2 + bb, 0.f);
    h1[3][t] = fmaxf(a3 + bb, 0.f);
  }
  __syncthreads();
  {
    int c = t & 127, rb = (t >> 7) * 2;
    float a0 = 0.f, a1 = 0.f;
    for (int k = 0; k < 256; k++) {
      float w = W2[k * 128 + c];
      a0 = fmaf(h1[rb][k], w, a0);
      a1 = fmaf(h1[rb + 1][k], w, a1);
    }
    float bb = b2[c];
    h2[rb][c] = fmaxf(a0 + bb, 0.f);
    h2[rb + 1][c] = fmaxf(a1 + bb, 0.f);
  }
  __syncthreads();
  {
    int c = t & 63, r = t >> 6;
    float a = 0.f;
    for (int k = 0; k < 128; k++) a = fmaf(h2[r][k], W3[k * 64 + c], a);
    h3[r][c] = fmaxf(a + b3[c], 0.f);
  }
  __syncthreads();
  {
    int r = t >> 6, l = t & 63;
    float v = h3[r][l] * Wc[l];
#pragma unroll
    for (int m = 32; m; m >>= 1) v += __shfl_down(v, m);
    if (l == 0) out[r0 + r] = v + bc[0];
  }
}

// ---------------------------------------------------------------------------
// Similarity, single-bf16 MFMA, symmetry-reduced grid, single-buffer LDS
// staging (proven 93-95 us).
// ---------------------------------------------------------------------------
__global__ __launch_bounds__(256) void k_simM(const ushort* __restrict__ Eb,
                                              const float* __restrict__ rn,
                                              ushort* __restrict__ S,
                                              double* __restrict__ meansum) {
  int x = blockIdx.x, y = blockIdx.y;
  if (x < 32 && y > x) return;
  __shared__ ushort Ei[128 * 40];
  __shared__ ushort Ej[128 * 40];
  __shared__ float redbuf[4];

  int t = threadIdx.x;
  int w = t >> 6, lane = t & 63;
  int m = lane & 15, g = lane >> 4;
  int ib = (w >> 1) * 64, jb = (w & 1) * 64;
  int i0 = x * 128, j0 = y * 128;

  floatx4 acc[4][4];
#pragma unroll
  for (int a = 0; a < 4; a++)
#pragma unroll
    for (int b = 0; b < 4; b++) acc[a][b] = (floatx4)0.0f;

  int lrow = t >> 1, lhalf = (t & 1) * 16;
  for (int kt = 0; kt < DIM; kt += 32) {
    __syncthreads();
    {
      const ushort* gi = Eb + (size_t)(i0 + lrow) * DIM + kt + lhalf;
      const ushort* gj = Eb + (size_t)(j0 + lrow) * DIM + kt + lhalf;
      int o = lrow * 40 + lhalf;
      *(short8*)&Ei[o]     = *(const short8*)gi;
      *(short8*)&Ei[o + 8] = *(const short8*)(gi + 8);
      *(short8*)&Ej[o]     = *(const short8*)gj;
      *(short8*)&Ej[o + 8] = *(const short8*)(gj + 8);
    }
    __syncthreads();

    short8 ah[4], bh[4];
#pragma unroll
    for (int rt = 0; rt < 4; rt++) ah[rt] = *(const short8*)&Ei[(ib + rt * 16 + m) * 40 + g * 8];
#pragma unroll
    for (int ct = 0; ct < 4; ct++) bh[ct] = *(const short8*)&Ej[(jb + ct * 16 + m) * 40 + g * 8];
#pragma unroll
    for (int rt = 0; rt < 4; rt++)
#pragma unroll
      for (int ct = 0; ct < 4; ct++)
        acc[rt][ct] = __builtin_amdgcn_mfma_f32_16x16x32_bf16(ah[rt], bh[ct], acc[rt][ct], 0, 0, 0);
  }

  bool dostore = (x >= 32);
  bool isdiag  = (x == y);
  float weight = (x < 32) ? (isdiag ? 1.0f : 2.0f) : ((y < 32) ? 2.0f : 1.0f);
  float lsum = 0.f;
#pragma unroll
  for (int rt = 0; rt < 4; rt++) {
    int gi0 = i0 + ib + rt * 16 + g * 4;
    float4 rni = *(const float4*)(rn + gi0);
#pragma unroll
    for (int ct = 0; ct < 4; ct++) {
      int gj = j0 + jb + ct * 16 + m;
      float rnj = rn[gj];
#pragma unroll
      for (int r = 0; r < 4; r++) {
        int gi = gi0 + r;
        float rv = (r == 0) ? rni.x : (r == 1) ? rni.y : (r == 2) ? rni.z : rni.w;
        float s = acc[rt][ct][r] * rv * rnj;
        if (isdiag && gi == gj) s = 0.f;
        s = fminf(fmaxf(s, 0.f), 1.f);
        lsum += s;
        if (dostore) S[(size_t)(gi - NLAB) * BROWS + gj] = f2bf(s);
      }
    }
  }
  lsum *= weight;
#pragma unroll
  for (int d = 1; d < 64; d <<= 1) lsum += __shfl_xor(lsum, d);
  if (lane == 0) redbuf[w] = lsum;
  __syncthreads();
  if (t == 0) atomicAdd(meansum, (double)(redbuf[0] + redbuf[1] + redbuf[2] + redbuf[3]));
}

// ---------------------------------------------------------------------------
// FALLBACK: one replicator iteration per launch (proven 696.8 us path).
// ---------------------------------------------------------------------------
__global__ __launch_bounds__(1024, 4) void k_iter(const ushort* __restrict__ S,
                                                  ushort* __restrict__ Au,
                                                  const ushort* __restrict__ XTr,
                                                  ushort* __restrict__ XTw,
                                                  float* __restrict__ Xu,
                                                  float* __restrict__ Plab,
                                                  float* __restrict__ hist,
                                                  float* __restrict__ errsq,
                                                  const double* __restrict__ ms,
                                                  int it) {
  if (it > 0 && errsq[it - 1] <= 1e-6f) return;
  __shared__ float part[8][16 * 113];
  __shared__ float Pbuf[16 * 114];
  __shared__ float dsqbuf[16];
  ushort* xbuf = (ushort*)&part[0][0];
  int t = threadIdx.x;
  int w = t >> 6, lane = t & 63;
  int m = lane & 15, g = lane >> 4;
  int r0 = blockIdx.x * 16;

  float2 xo = make_float2(0.f, 0.f);
  if (lane < 56) xo = *(const float2*)(Xu + (size_t)(r0 + w) * CPAD + lane * 2);
  float pl_pre[2] = {0.f, 0.f};
  if (it > 0) {
#pragma unroll
    for (int q = 0; q < 2; q++) {
      int idx = t + q * 1024;
      if (idx < 16 * CPAD)
        pl_pre[q] = Plab[(size_t)(r0 + idx / CPAD) * CPAD + idx % CPAD];
    }
  }

  floatx4 acc[7];
#pragma unroll
  for (int c = 0; c < 7; c++) acc[c] = (floatx4)0.0f;

  if (it == 0) {
    float mean = (float)(ms[0] * (1.0 / ((double)BROWS * (double)BROWS)));
    int kw = w * 512;
    for (int ks = 0; ks < 16; ks++) {
      int kk = kw + ks * 32;
      size_t so = (size_t)(r0 + m) * BROWS + kk + g * 8;
      short8 a = *(const short8*)(S + so);
      union { short8 v; ushort u[8]; } ua; ua.v = a;
#pragma unroll
      for (int e = 0; e < 8; e++) {
        float s = bf2f(ua.u[e]);
        float av = (s < mean) ? 1.0f : 1.0f - s;
        ua.u[e] = f2bf(av);
      }
      a = ua.v;
      if (w >= 8)
        *(short8*)(Au + (size_t)(r0 + m) * NUNL + (kk - NLAB) + g * 8) = a;
#pragma unroll
      for (int ct = 0; ct < 7; ct++) {
        short8 b = *(const short8*)(XTr + (size_t)(ct * 16 + m) * BROWS + kk + g * 8);
        acc[ct] = __builtin_amdgcn_mfma_f32_16x16x32_bf16(a, b, acc[ct], 0, 0, 0);
      }
    }
  } else {
    int kw = w * 256;
    size_t abase = (size_t)(r0 + m) * NUNL + kw + g * 8;
    size_t bbase = (size_t)m * BROWS + NLAB + kw + g * 8;
    for (int ks = 0; ks < 8; ks++) {
      short8 a = *(const short8*)(Au + abase + ks * 32);
#pragma unroll
      for (int ct = 0; ct < 7; ct++) {
        short8 b = *(const short8*)(XTr + bbase + (size_t)ct * 16 * BROWS + ks * 32);
        acc[ct] = __builtin_amdgcn_mfma_f32_16x16x32_bf16(a, b, acc[ct], 0, 0, 0);
      }
    }
  }

  if (w < 8) {
#pragma unroll
    for (int ct = 0; ct < 7; ct++)
#pragma unroll
      for (int r = 0; r < 4; r++)
        part[w][(g * 4 + r) * 113 + ct * 16 + m] = acc[ct][r];
  }
  __syncthreads();
  float sA[2] = {0.f, 0.f}, sB[2] = {0.f, 0.f};
#pragma unroll
  for (int q = 0; q < 2; q++) {
    int idx = t + q * 1024;
    if (idx < 16 * CPAD) {
      int row = idx / CPAD, col = idx % CPAD;
      int o = row * 113 + col;
      sA[q] = ((part[0][o] + part[1][o]) + (part[2][o] + part[3][o]))
            + ((part[4][o] + part[5][o]) + (part[6][o] + part[7][o]));
    }
  }
  __syncthreads();
  if (w >= 8) {
#pragma unroll
    for (int ct = 0; ct < 7; ct++)
#pragma unroll
      for (int r = 0; r < 4; r++)
        part[w - 8][(g * 4 + r) * 113 + ct * 16 + m] = acc[ct][r];
  }
  __syncthreads();
#pragma unroll
  for (int q = 0; q < 2; q++) {
    int idx = t + q * 1024;
    if (idx < 16 * CPAD) {
      int row = idx / CPAD, col = idx % CPAD;
      int o = row * 113 + col;
      sB[q] = ((part[0][o] + part[1][o]) + (part[2][o] + part[3][o]))
            + ((part[4][o] + part[5][o]) + (part[6][o] + part[7][o]));
      float P;
      size_t go = (size_t)(r0 + row) * CPAD + col;
      if (it == 0) { Plab[go] = sA[q]; P = sA[q] + sB[q]; }
      else         { P = sA[q] + sB[q] + pl_pre[q]; }
      Pbuf[row * 114 + col] = P;
    }
  }
  __syncthreads();

  int gr = r0 + w;
  bool act = lane < 56;
  float2 p = make_float2(0.f, 0.f);
  if (act) p = *(const float2*)&Pbuf[w * 114 + lane * 2];
  float2 xn;
  xn.x = xo.x * p.x;
  xn.y = xo.y * p.y;
  float s = xn.x + xn.y;
#pragma unroll
  for (int d = 1; d < 64; d <<= 1) s += __shfl_xor(s, d);
  float inv = 1.0f / s;
  float ent = 0.f, dsq = 0.f;
  if (act) {
    xn.x *= inv; xn.y *= inv;
    ent = -(xn.x * log2f(xn.x + 1e-20f) + xn.y * log2f(xn.y + 1e-20f));
    float dx = xn.x - xo.x, dy = xn.y - xo.y;
    dsq = dx * dx + dy * dy;
    *(float2*)(Xu + (size_t)gr * CPAD + lane * 2) = xn;
    int c0 = lane * 2;
    xbuf[c0 * 18 + w]       = f2bf(xn.x);
    xbuf[(c0 + 1) * 18 + w] = f2bf(xn.y);
  }
#pragma unroll
  for (int d = 1; d < 64; d <<= 1) { ent += __shfl_xor(ent, d); dsq += __shfl_xor(dsq, d); }
  if (lane == 0) {
    hist[gr] += ent;
    dsqbuf[w] = dsq;
  }
  __syncthreads();

  if (t < CPAD * 8) {
    int c = t >> 3, jl = (t & 7) * 2;
    ushort2 v = *(const ushort2*)&xbuf[c * 18 + jl];
    *(ushort2*)(XTw + (size_t)c * BROWS + NLAB + r0 + jl) = v;
  }
  if (t == 0) {
    float ds = 0.f;
#pragma unroll
    for (int i = 0; i < 16; i++) ds += dsqbuf[i];
    atomicAdd(&errsq[it], ds);
  }
}

__global__ __launch_bounds__(256) void k_final(const float* __restrict__ hist,
                                               float* __restrict__ out) {
  int i = blockIdx.x * 256 + threadIdx.x;
  float yt = (i < NLAB) ? 0.0f : hist[i - NLAB] * (1.0f / 30.0f);
  out[BROWS + i] = yt;
  out[2 * BROWS + i] = (i < NLAB) ? 1.0f : 0.0f;
}

// ---------------------------------------------------------------------------
// NEW: persistent cooperative loop.  One block per 16 unlabeled rows, 512
// threads (8 waves), 1 block/CU.  Fuses initX + 30 iterations + final.
//   * Au slice (16x4096 bf16, 128 KiB) lives in LDS across all iterations,
//     XOR-swizzled (byte ^= (m&7)<<4) so the stride-8KiB row reads are
//     bank-balanced (8 accesses/bank = the b128 minimum, vs 16 unswizzled).
//   * Xu (exact X), Plab (labeled-K partial), hist -> registers.
//   * Per-iteration grid.sync() replaces 30 kernel launches; converged
//     break is uniform (all blocks read the same errsq[it]).
// Reduction: 8 wave-partials in two deterministic 4-partial phases
// (tree order ((p0+p1)+(p2+p3)) preserved).
// ---------------------------------------------------------------------------
__global__ __launch_bounds__(512, 2) void k_loop(const ushort* __restrict__ S,
                                                 ushort* __restrict__ XT0,
                                                 ushort* __restrict__ XT1,
                                                 const int* __restrict__ labels,
                                                 const double* __restrict__ ms,
                                                 float* __restrict__ errs,
                                                 float* __restrict__ out) {
  extern __shared__ char ldsbase[];
  ushort* AuL  = (ushort*)ldsbase;                       // 131072 B, swizzled
  float*  part = (float*)(ldsbase + 131072);             // 4 bufs x 16*113 = 28928 B
  float*  dsqb = (float*)(ldsbase + 131072 + 28928);     // 8 floats
  float*  Pbuf = part;                                   // alias: 16*114 floats (7296 B)
  ushort* xbuf = (ushort*)(ldsbase + 131072 + 7296);     // alias: 112*18 ushort (4032 B)

  cg::grid_group grid = cg::this_grid();
  int t = threadIdx.x;
  int w = t >> 6, lane = t & 63;
  int m = lane & 15, g = lane >> 4;
  int r0 = blockIdx.x * 16;
  bool act = lane < 56;

  // ---- persistent register state ----
  float2 xo[2];
#pragma unroll
  for (int rr = 0; rr < 2; rr++) {
    xo[rr].x = (act && (lane * 2     < CREAL)) ? 0.01f : 0.f;
    xo[rr].y = (act && (lane * 2 + 1 < CREAL)) ? 0.01f : 0.f;
  }
  float pl_pre[4] = {0.f, 0.f, 0.f, 0.f};
  float hacc[2] = {0.f, 0.f};

  // ---- fused init: X^T (both buffers) + labeled outputs ----
  int gtid = blockIdx.x * 512 + t;
  for (int i = gtid; i < CPAD * BROWS; i += 256 * 512) {
    int c = i >> 13, j = i & 8191;
    float v;
    if (j < NLAB) v = (labels[j] == c) ? 1.0f : 0.0f;
    else          v = (c < CREAL) ? 0.01f : 0.0f;
    ushort b = f2bf(v);
    XT0[i] = b;
    XT1[i] = b;
  }
  if (gtid < NLAB) {
    out[BROWS + gtid] = 0.0f;                 // labeled y_true
    out[2 * BROWS + gtid] = 1.0f;             // labeled mask
    out[2 * BROWS + NLAB + gtid] = 0.0f;      // unlabeled mask
  }
  __threadfence();
  grid.sync();

  for (int it = 0; it < MAXIT; it++) {
    const ushort* XTr = (it & 1) ? XT1 : XT0;
    ushort*       XTw = (it & 1) ? XT0 : XT1;

    floatx4 acc[7];
#pragma unroll
    for (int c = 0; c < 7; c++) acc[c] = (floatx4)0.0f;

    if (it == 0) {
      float mean = (float)(ms[0] * (1.0 / ((double)BROWS * (double)BROWS)));
      int kw = w * 1024;                      // wave w: k in [w*1024, +1024)
      for (int ks = 0; ks < 32; ks++) {
        int kk = kw + ks * 32;
        size_t so = (size_t)(r0 + m) * BROWS + kk + g * 8;
        short8 a = *(const short8*)(S + so);
        union { short8 v; ushort u[8]; } ua; ua.v = a;
#pragma unroll
        for (int e = 0; e < 8; e++) {
          float s = bf2f(ua.u[e]);
          float av = (s < mean) ? 1.0f : 1.0f - s;
          ua.u[e] = f2bf(av);
        }
        a = ua.v;
        if (w >= 4) {                         // unlabeled K half -> persist in LDS
          int kbyte = ((kk - NLAB) + g * 8) * 2;
          *(short8*)((char*)AuL + ((m << 13) | (kbyte ^ ((m & 7) << 4)))) = a;
        }
#pragma unroll
        for (int ct = 0; ct < 7; ct++) {
          short8 b = *(const short8*)(XTr + (size_t)(ct * 16 + m) * BROWS + kk + g * 8);
          acc[ct] = __builtin_amdgcn_mfma_f32_16x16x32_bf16(a, b, acc[ct], 0, 0, 0);
        }
      }
    } else {
      int kw = w * 512;                       // Au-relative: wave w k in [w*512, +512)
      for (int ks = 0; ks < 16; ks++) {
        int krel = kw + ks * 32;
        int kbyte = (krel + g * 8) * 2;
        short8 a = *(const short8*)((const char*)AuL + ((m << 13) | (kbyte ^ ((m & 7) << 4))));
        size_t bb = (size_t)m * BROWS + NLAB + krel + g * 8;
#pragma unroll
        for (int ct = 0; ct < 7; ct++) {
          short8 b = *(const short8*)(XTr + bb + (size_t)ct * 16 * BROWS);
          acc[ct] = __builtin_amdgcn_mfma_f32_16x16x32_bf16(a, b, acc[ct], 0, 0, 0);
        }
      }
    }

    // ---- deterministic two-phase reduction (4 partials each) ----
    if (w < 4) {
#pragma unroll
      for (int ct = 0; ct < 7; ct++)
#pragma unroll
        for (int r = 0; r < 4; r++)
          part[w * 1808 + (g * 4 + r) * 113 + ct * 16 + m] = acc[ct][r];
    }
    __syncthreads();
    float sA[4] = {0.f, 0.f, 0.f, 0.f}, sB[4] = {0.f, 0.f, 0.f, 0.f};
#pragma unroll
    for (int q = 0; q < 4; q++) {
      int idx = t + q * 512;
      if (idx < 16 * CPAD) {
        int o = (idx / CPAD) * 113 + idx % CPAD;
        sA[q] = (part[o] + part[1808 + o]) + (part[2 * 1808 + o] + part[3 * 1808 + o]);
      }
    }
    __syncthreads();
    if (w >= 4) {
#pragma unroll
      for (int ct = 0; ct < 7; ct++)
#pragma unroll
        for (int r = 0; r < 4; r++)
          part[(w - 4) * 1808 + (g * 4 + r) * 113 + ct * 16 + m] = acc[ct][r];
    }
    __syncthreads();
#pragma unroll
    for (int q = 0; q < 4; q++) {
      int idx = t + q * 512;
      if (idx < 16 * CPAD) {
        int o = (idx / CPAD) * 113 + idx % CPAD;
        sB[q] = (part[o] + part[1808 + o]) + (part[2 * 1808 + o] + part[3 * 1808 + o]);
      }
    }
    __syncthreads();                          // all part reads done -> Pbuf alias safe
#pragma unroll
    for (int q = 0; q < 4; q++) {
      int idx = t + q * 512;
      if (idx < 16 * CPAD) {
        int row = idx / CPAD, col = idx % CPAD;
        float P;
        if (it == 0) { pl_pre[q] = sA[q]; P = sA[q] + sB[q]; }   // phase A = labeled K
        else         { P = sA[q] + sB[q] + pl_pre[q]; }
        Pbuf[row * 114 + col] = P;
      }
    }
    __syncthreads();

    // ---- fused epilogue: wave w handles rows 2w, 2w+1 ----
    float dtot = 0.f;
#pragma unroll
    for (int rr = 0; rr < 2; rr++) {
      int rw = w * 2 + rr;
      float2 p = make_float2(0.f, 0.f);
      if (act) p = *(const float2*)&Pbuf[rw * 114 + lane * 2];
      float2 xn;
      xn.x = xo[rr].x * p.x;
      xn.y = xo[rr].y * p.y;
      float s = xn.x + xn.y;
#pragma unroll
      for (int d = 1; d < 64; d <<= 1) s += __shfl_xor(s, d);
      float inv = 1.0f / s;
      float ent = 0.f, dsq = 0.f;
      if (act) {
        xn.x *= inv; xn.y *= inv;
        ent = -(xn.x * log2f(xn.x + 1e-20f) + xn.y * log2f(xn.y + 1e-20f));
        float dx = xn.x - xo[rr].x, dy = xn.y - xo[rr].y;
        dsq = dx * dx + dy * dy;
        xo[rr] = xn;
        int c0 = lane * 2;
        xbuf[c0 * 18 + rw]       = f2bf(xn.x);
        xbuf[(c0 + 1) * 18 + rw] = f2bf(xn.y);
      }
#pragma unroll
      for (int d = 1; d < 64; d <<= 1) { ent += __shfl_xor(ent, d); dsq += __shfl_xor(dsq, d); }
      if (lane == 0) hacc[rr] += ent;
      dtot += dsq;
    }
    if (lane == 0) dsqb[w] = dtot;
    __syncthreads();

    // ---- coalesced X^T write-back ----
#pragma unroll
    for (int q = 0; q < 2; q++) {
      int tt = t + q * 512;
      if (tt < CPAD * 8) {
        int c = tt >> 3, jl = (tt & 7) * 2;
        ushort2 v = *(const ushort2*)&xbuf[c * 18 + jl];
        *(ushort2*)(XTw + (size_t)c * BROWS + NLAB + r0 + jl) = v;
      }
    }
    if (t == 0) {
      float ds = 0.f;
#pragma unroll
      for (int i = 0; i < 8; i++) ds += dsqb[i];
      atomicAdd(&errs[it], ds);
    }
    __threadfence();
    grid.sync();
    if (*((volatile const float*)errs + it) <= 1e-6f) break;   // uniform
  }

  // ---- final: y_true for this block's rows ----
  if (lane == 0) {
#pragma unroll
    for (int rr = 0; rr < 2; rr++)
      out[BROWS + NLAB + r0 + w * 2 + rr] = hacc[rr] * (1.0f / 30.0f);
  }
}

// ---------------------------------------------------------------------------
extern "C" void kernel_launch(void* const* d_in, const int* in_sizes, int n_in,
                              void* d_out, int out_size, void* d_ws, size_t ws_size,
                              hipStream_t stream) {
  const float* emb    = (const float*)d_in[1];
  const int*   labels = (const int*)d_in[2];
  const float* W1 = (const float*)d_in[3];
  const float* b1 = (const float*)d_in[4];
  const float* W2 = (const float*)d_in[5];
  const float* b2 = (const float*)d_in[6];
  const float* W3 = (const float*)d_in[7];
  const float* b3 = (const float*)d_in[8];
  const float* Wc = (const float*)d_in[9];
  const float* bc = (const float*)d_in[10];
  float* out = (float*)d_out;

  char* ws = (char*)d_ws;
  ushort* S    = (ushort*)(ws + OFF_S);
  ushort* Au   = (ushort*)(ws + OFF_AU);
  ushort* Eb   = (ushort*)(ws + OFF_EB);
  ushort* XT0  = (ushort*)(ws + OFF_XT0);
  ushort* XT1  = (ushort*)(ws + OFF_XT1);
  float*  Xu   = (float*)(ws + OFF_XU);
  float*  Plab = (float*)(ws + OFF_PL);
  float*  hist = (float*)(ws + OFF_HIST);
  float*  errs = (float*)(ws + OFF_ERR);
  double* ms   = (double*)(ws + OFF_MS);
  float*  rn   = (float*)(ws + OFF_RN);

  // zero hist + errsq + mean accumulator
  hipMemsetAsync(ws + OFF_HIST, 0, MEMSET_LEN, stream);

  k_prep<<<BROWS, 64, 0, stream>>>(emb, Eb, rn);
  k_mlp<<<BROWS / 4, 256, 0, stream>>>(emb, W1, b1, W2, b2, W3, b3, Wc, bc, out);

  { dim3 g(BROWS / 128, BROWS / 128); k_simM<<<g, 256, 0, stream>>>(Eb, rn, S, ms); }

  // ---- preferred: persistent cooperative loop (initX + 30 iters + final) ----
  (void)hipFuncSetAttribute((const void*)k_loop,
                            hipFuncAttributeMaxDynamicSharedMemorySize, (int)DLDS);
  void* cargs[7] = {(void*)&S, (void*)&XT0, (void*)&XT1, (void*)&labels,
                    (void*)&ms, (void*)&errs, (void*)&out};
  hipError_t ce = hipLaunchCooperativeKernel((const void*)k_loop,
                                             dim3(NUNL / 16), dim3(512),
                                             cargs, DLDS, stream);
  if (ce != hipSuccess) {
    // ---- fallback: proven multi-launch path (696.8 us) ----
    (void)hipGetLastError();
    { dim3 g(BROWS / 256, CPAD); k_initX<<<g, 256, 0, stream>>>(XT0, XT1, Xu, labels); }
    for (int it = 0; it < MAXIT; it++) {
      const ushort* XTr = (it & 1) ? XT1 : XT0;
      ushort*       XTw = (it & 1) ? XT0 : XT1;
      k_iter<<<NUNL / 16, 1024, 0, stream>>>(S, Au, XTr, XTw, Xu, Plab, hist, errs, ms, it);
    }
    k_final<<<BROWS / 256, 256, 0, stream>>>(hist, out);
  }
}

// Round 3
// 799.519 us; speedup vs baseline: 2.0282x; 2.0282x over previous
//
#include <hip/hip_runtime.h>
#include <hip/hip_bf16.h>
#include <math.h>

// ---------------------------------------------------------------------------
// Problem constants
// ---------------------------------------------------------------------------
namespace {
constexpr int BROWS = 8192;
constexpr int NLAB  = 4096;
constexpr int NUNL  = 4096;
constexpr int CREAL = 100;
constexpr int CPAD  = 112;    // 7 mfma col-tiles of 16
constexpr int DIM   = 512;
constexpr int MAXIT = 30;

constexpr size_t MiB = 1ull << 20;
// ws layout (bytes).
constexpr size_t OFF_S    = 0;              // ushort[4096][8192] raw S  64 MiB (dead after it0)
constexpr size_t OFF_AU   = 64 * MiB;       // ushort[4096][4096] thresholded A (unlabeled K) 32 MiB
constexpr size_t OFF_EB   = 96 * MiB;       // ushort[8192][512] emb bf16 (dead after simM) 8 MiB
// overlay of EB after simM:
constexpr size_t OFF_XT0  = 96 * MiB;       // ushort[112][8192] X^T ping 1.75 MiB
constexpr size_t OFF_XT1  = 98 * MiB;       // X^T pong
constexpr size_t OFF_XU   = 100 * MiB;      // float[4096][112] exact X (unlabeled)
constexpr size_t OFF_PL   = 102 * MiB;      // float[4096][112] P_lab (static after it0)
// tail (never overlaid):
constexpr size_t OFF_HIST = 104 * MiB;          // float[4096]
constexpr size_t OFF_ERR  = 104 * MiB + 16384;  // float[32]
constexpr size_t OFF_MS   = 104 * MiB + 16768;  // double
constexpr size_t OFF_RN   = 104 * MiB + 32768;  // float[8192]
constexpr size_t MEMSET_LEN = 20480;            // HIST..MS inclusive
}

typedef __attribute__((ext_vector_type(8))) short short8;
typedef __attribute__((ext_vector_type(4))) float floatx4;

__device__ inline ushort f2bf(float f) {
  __hip_bfloat16 h = __float2bfloat16(f);
  union { __hip_bfloat16 b; ushort u; } c; c.b = h; return c.u;
}
__device__ inline float bf2f(ushort u) {
  union { ushort u; __hip_bfloat16 b; } c; c.u = u;
  return __bfloat162float(c.b);
}

// ---------------------------------------------------------------------------
// Fused: row 1/norm + emb fp32 -> bf16 cast.  One block per row, 64 lanes.
// ---------------------------------------------------------------------------
__global__ __launch_bounds__(64) void k_prep(const float* __restrict__ emb,
                                             ushort* __restrict__ Eb,
                                             float* __restrict__ rn) {
  int row = blockIdx.x, l = threadIdx.x;
  const float4* e4 = (const float4*)(emb + (size_t)row * DIM);
  float4 a = e4[2 * l], b = e4[2 * l + 1];
  float f[8] = {a.x, a.y, a.z, a.w, b.x, b.y, b.z, b.w};
  float s = 0.f;
#pragma unroll
  for (int q = 0; q < 8; q++) s += f[q] * f[q];
#pragma unroll
  for (int m = 1; m < 64; m <<= 1) s += __shfl_xor(s, m);
  if (l == 0) rn[row] = 1.0f / fmaxf(sqrtf(s), 1e-12f);
  union { short8 v; ushort u[8]; } o;
#pragma unroll
  for (int q = 0; q < 8; q++) o.u[q] = f2bf(f[q]);
  *(short8*)(Eb + (size_t)row * DIM + l * 8) = o.v;
}

// ---------------------------------------------------------------------------
// X init: bf16 X^T in both ping-pong buffers + exact fp32 unlabeled X
// ---------------------------------------------------------------------------
__global__ __launch_bounds__(256) void k_initX(ushort* __restrict__ X0,
                                               ushort* __restrict__ X1,
                                               float* __restrict__ Xu,
                                               const int* __restrict__ labels) {
  int j = blockIdx.x * 256 + threadIdx.x;       // 0..8191
  int c = blockIdx.y;                            // 0..111
  float v;
  if (j < NLAB) v = (labels[j] == c) ? 1.0f : 0.0f;
  else          v = (c < CREAL) ? 0.01f : 0.0f;
  ushort b = f2bf(v);
  X0[(size_t)c * BROWS + j] = b;
  X1[(size_t)c * BROWS + j] = b;
  if (j >= NLAB) Xu[(size_t)(j - NLAB) * CPAD + c] = (c < CREAL) ? 0.01f : 0.0f;
}

// ---------------------------------------------------------------------------
// MLP 512->256->128->64->1.  16 rows/block (was 4): W1/W2/W3 L2 traffic /4
// (1 GB -> 256 MB).  Per-output k-order and final shuffle tree identical to
// the verified 4-row version -> bitwise-identical y_pred.
// ---------------------------------------------------------------------------
__global__ __launch_bounds__(256) void k_mlp(const float* __restrict__ emb,
                                             const float* __restrict__ W1, const float* __restrict__ b1,
                                             const float* __restrict__ W2, const float* __restrict__ b2,
                                             const float* __restrict__ W3, const float* __restrict__ b3,
                                             const float* __restrict__ Wc, const float* __restrict__ bc,
                                             float* __restrict__ out) {
  __shared__ float xs[16][512];   // 32 KB
  __shared__ float h1[16][256];   // 16 KB
  __shared__ float h2[16][128];   //  8 KB
  __shared__ float h3[16][64];    //  4 KB  (total 60 KB, 2 blocks/CU)
  int t = threadIdx.x;
  int r0 = blockIdx.x * 16;
  {
    const float4* src = (const float4*)(emb + (size_t)r0 * DIM);
    float4* dst = (float4*)&xs[0][0];
#pragma unroll
    for (int q = 0; q < 8; q++) dst[t + q * 256] = src[t + q * 256];
  }
  __syncthreads();
  {
    float a[16];
#pragma unroll
    for (int r = 0; r < 16; r++) a[r] = 0.f;
    for (int k = 0; k < 512; k++) {
      float wv = W1[k * 256 + t];
#pragma unroll
      for (int r = 0; r < 16; r++) a[r] = fmaf(xs[r][k], wv, a[r]);
    }
    float bb = b1[t];
#pragma unroll
    for (int r = 0; r < 16; r++) h1[r][t] = fmaxf(a[r] + bb, 0.f);
  }
  __syncthreads();
  {
    int c = t & 127, rb = (t >> 7) * 8;
    float a[8];
#pragma unroll
    for (int r = 0; r < 8; r++) a[r] = 0.f;
    for (int k = 0; k < 256; k++) {
      float wv = W2[k * 128 + c];
#pragma unroll
      for (int r = 0; r < 8; r++) a[r] = fmaf(h1[rb + r][k], wv, a[r]);
    }
    float bb = b2[c];
#pragma unroll
    for (int r = 0; r < 8; r++) h2[rb + r][c] = fmaxf(a[r] + bb, 0.f);
  }
  __syncthreads();
  {
    int c = t & 63, rb = (t >> 6) * 4;
    float a[4];
#pragma unroll
    for (int r = 0; r < 4; r++) a[r] = 0.f;
    for (int k = 0; k < 128; k++) {
      float wv = W3[k * 64 + c];
#pragma unroll
      for (int r = 0; r < 4; r++) a[r] = fmaf(h2[rb + r][k], wv, a[r]);
    }
#pragma unroll
    for (int r = 0; r < 4; r++) h3[rb + r][c] = fmaxf(a[r] + b3[c], 0.f);
  }
  __syncthreads();
  {
    int w = t >> 6, l = t & 63;
#pragma unroll
    for (int rr = 0; rr < 4; rr++) {
      int r = w * 4 + rr;
      float v = h3[r][l] * Wc[l];
#pragma unroll
      for (int mm = 32; mm; mm >>= 1) v += __shfl_down(v, mm);
      if (l == 0) out[r0 + r] = v + bc[0];
    }
  }
}

// ---------------------------------------------------------------------------
// Similarity (proven 93-95 us, unchanged).
// ---------------------------------------------------------------------------
__global__ __launch_bounds__(256) void k_simM(const ushort* __restrict__ Eb,
                                              const float* __restrict__ rn,
                                              ushort* __restrict__ S,
                                              double* __restrict__ meansum) {
  int x = blockIdx.x, y = blockIdx.y;
  if (x < 32 && y > x) return;
  __shared__ ushort Ei[128 * 40];
  __shared__ ushort Ej[128 * 40];
  __shared__ float redbuf[4];

  int t = threadIdx.x;
  int w = t >> 6, lane = t & 63;
  int m = lane & 15, g = lane >> 4;
  int ib = (w >> 1) * 64, jb = (w & 1) * 64;
  int i0 = x * 128, j0 = y * 128;

  floatx4 acc[4][4];
#pragma unroll
  for (int a = 0; a < 4; a++)
#pragma unroll
    for (int b = 0; b < 4; b++) acc[a][b] = (floatx4)0.0f;

  int lrow = t >> 1, lhalf = (t & 1) * 16;
  for (int kt = 0; kt < DIM; kt += 32) {
    __syncthreads();
    {
      const ushort* gi = Eb + (size_t)(i0 + lrow) * DIM + kt + lhalf;
      const ushort* gj = Eb + (size_t)(j0 + lrow) * DIM + kt + lhalf;
      int o = lrow * 40 + lhalf;
      *(short8*)&Ei[o]     = *(const short8*)gi;
      *(short8*)&Ei[o + 8] = *(const short8*)(gi + 8);
      *(short8*)&Ej[o]     = *(const short8*)gj;
      *(short8*)&Ej[o + 8] = *(const short8*)(gj + 8);
    }
    __syncthreads();

    short8 ah[4], bh[4];
#pragma unroll
    for (int rt = 0; rt < 4; rt++) ah[rt] = *(const short8*)&Ei[(ib + rt * 16 + m) * 40 + g * 8];
#pragma unroll
    for (int ct = 0; ct < 4; ct++) bh[ct] = *(const short8*)&Ej[(jb + ct * 16 + m) * 40 + g * 8];
#pragma unroll
    for (int rt = 0; rt < 4; rt++)
#pragma unroll
      for (int ct = 0; ct < 4; ct++)
        acc[rt][ct] = __builtin_amdgcn_mfma_f32_16x16x32_bf16(ah[rt], bh[ct], acc[rt][ct], 0, 0, 0);
  }

  bool dostore = (x >= 32);
  bool isdiag  = (x == y);
  float weight = (x < 32) ? (isdiag ? 1.0f : 2.0f) : ((y < 32) ? 2.0f : 1.0f);
  float lsum = 0.f;
#pragma unroll
  for (int rt = 0; rt < 4; rt++) {
    int gi0 = i0 + ib + rt * 16 + g * 4;
    float4 rni = *(const float4*)(rn + gi0);
#pragma unroll
    for (int ct = 0; ct < 4; ct++) {
      int gj = j0 + jb + ct * 16 + m;
      float rnj = rn[gj];
#pragma unroll
      for (int r = 0; r < 4; r++) {
        int gi = gi0 + r;
        float rv = (r == 0) ? rni.x : (r == 1) ? rni.y : (r == 2) ? rni.z : rni.w;
        float s = acc[rt][ct][r] * rv * rnj;
        if (isdiag && gi == gj) s = 0.f;
        s = fminf(fmaxf(s, 0.f), 1.f);
        lsum += s;
        if (dostore) S[(size_t)(gi - NLAB) * BROWS + gj] = f2bf(s);
      }
    }
  }
  lsum *= weight;
#pragma unroll
  for (int d = 1; d < 64; d <<= 1) lsum += __shfl_xor(lsum, d);
  if (lane == 0) redbuf[w] = lsum;
  __syncthreads();
  if (t == 0) atomicAdd(meansum, (double)(redbuf[0] + redbuf[1] + redbuf[2] + redbuf[3]));
}

// ---------------------------------------------------------------------------
// One replicator iteration.  32 rows/block, grid 128 (was 16 rows, grid 256):
// each XT B-fragment feeds 2 A-row-tiles (14 MFMA : 7 B-loads), and total
// XT L2 traffic halves (229 -> 114 MB/iter).  k-split per wave unchanged
// (it0: w*512, it>0: w*256) and reduction tree preserved exactly:
//   sA = ((p0+p1)+(p2+p3)) + ((p4+p5)+(p6+p7)),  P = (sA+sB)+pl
// via 4 phases of 4 partial buffers -> bitwise-identical output.
// Pbuf and xbuf alias `part` (after last read) to stay under 64 KB static LDS.
// ---------------------------------------------------------------------------
__global__ __launch_bounds__(1024, 4) void k_iter(const ushort* __restrict__ S,
                                                  ushort* __restrict__ Au,
                                                  const ushort* __restrict__ XTr,
                                                  ushort* __restrict__ XTw,
                                                  float* __restrict__ Xu,
                                                  float* __restrict__ Plab,
                                                  float* __restrict__ hist,
                                                  float* __restrict__ errsq,
                                                  const double* __restrict__ ms,
                                                  int it) {
  if (it > 0 && errsq[it - 1] <= 1e-6f) return;
  __shared__ float part[4][32 * 113];   // 57856 B
  __shared__ float dsqb[16];
  float*  Pbuf = &part[0][0];                              // [32][114] = 14592 B
  ushort* xbuf = (ushort*)((char*)&part[0][0] + 16384);    // [112][34] =  7616 B (disjoint from Pbuf)

  int t = threadIdx.x;
  int w = t >> 6, lane = t & 63;
  int m = lane & 15, g = lane >> 4;
  int r0 = blockIdx.x * 32;             // unlabeled row base

  // ---- entry prefetches (latency hidden behind GEMM phase) ----
  float2 xo[2];
  xo[0] = make_float2(0.f, 0.f); xo[1] = make_float2(0.f, 0.f);
  if (lane < 56) {
    xo[0] = *(const float2*)(Xu + (size_t)(r0 + w * 2)     * CPAD + lane * 2);
    xo[1] = *(const float2*)(Xu + (size_t)(r0 + w * 2 + 1) * CPAD + lane * 2);
  }
  float pl_pre[4] = {0.f, 0.f, 0.f, 0.f};
  if (it > 0) {
#pragma unroll
    for (int q = 0; q < 4; q++) {
      int idx = t + q * 1024;
      if (idx < 32 * CPAD)
        pl_pre[q] = Plab[(size_t)(r0 + idx / CPAD) * CPAD + idx % CPAD];
    }
  }

  floatx4 acc[2][7];
#pragma unroll
  for (int rt = 0; rt < 2; rt++)
#pragma unroll
    for (int c = 0; c < 7; c++) acc[rt][c] = (floatx4)0.0f;

  if (it == 0) {
    float mean = (float)(ms[0] * (1.0 / ((double)BROWS * (double)BROWS)));
    int kw = w * 512;                   // wave w: k in [w*512, +512)
    for (int ks = 0; ks < 16; ks++) {
      int kk = kw + ks * 32;
      short8 a[2];
#pragma unroll
      for (int rt = 0; rt < 2; rt++) {
        size_t so = (size_t)(r0 + rt * 16 + m) * BROWS + kk + g * 8;
        union { short8 v; ushort u[8]; } ua;
        ua.v = *(const short8*)(S + so);
#pragma unroll
        for (int e = 0; e < 8; e++) {
          float s = bf2f(ua.u[e]);
          float av = (s < mean) ? 1.0f : 1.0f - s;
          ua.u[e] = f2bf(av);
        }
        a[rt] = ua.v;
        if (w >= 8)   // unlabeled K half -> persist for it>0
          *(short8*)(Au + (size_t)(r0 + rt * 16 + m) * NUNL + (kk - NLAB) + g * 8) = a[rt];
      }
#pragma unroll
      for (int ct = 0; ct < 7; ct++) {
        short8 b = *(const short8*)(XTr + (size_t)(ct * 16 + m) * BROWS + kk + g * 8);
        acc[0][ct] = __builtin_amdgcn_mfma_f32_16x16x32_bf16(a[0], b, acc[0][ct], 0, 0, 0);
        acc[1][ct] = __builtin_amdgcn_mfma_f32_16x16x32_bf16(a[1], b, acc[1][ct], 0, 0, 0);
      }
    }
  } else {
    int kw = w * 256;                   // Au-relative: wave w k in [w*256, +256)
    size_t a0b = (size_t)(r0 + m)      * NUNL + kw + g * 8;
    size_t a1b = (size_t)(r0 + 16 + m) * NUNL + kw + g * 8;
    size_t bb  = (size_t)m * BROWS + NLAB + kw + g * 8;
    for (int ks = 0; ks < 8; ks++) {
      short8 a0 = *(const short8*)(Au + a0b + ks * 32);
      short8 a1 = *(const short8*)(Au + a1b + ks * 32);
#pragma unroll
      for (int ct = 0; ct < 7; ct++) {
        short8 b = *(const short8*)(XTr + bb + (size_t)ct * 16 * BROWS + ks * 32);
        acc[0][ct] = __builtin_amdgcn_mfma_f32_16x16x32_bf16(a0, b, acc[0][ct], 0, 0, 0);
        acc[1][ct] = __builtin_amdgcn_mfma_f32_16x16x32_bf16(a1, b, acc[1][ct], 0, 0, 0);
      }
    }
  }

  // ---- 4-phase reduction of 16 wave-partials through 4 LDS buffers ----
  // (D-frag map: row = rt*16 + g*4 + r, col = ct*16 + m)
  float sA[4], sB[4];
  for (int p = 0; p < 4; p++) {
    if ((w >> 2) == p) {
#pragma unroll
      for (int rt = 0; rt < 2; rt++)
#pragma unroll
        for (int ct = 0; ct < 7; ct++)
#pragma unroll
          for (int r = 0; r < 4; r++)
            part[w & 3][(rt * 16 + g * 4 + r) * 113 + ct * 16 + m] = acc[rt][ct][r];
    }
    __syncthreads();
#pragma unroll
    for (int q = 0; q < 4; q++) {
      int idx = t + q * 1024;
      if (idx < 32 * CPAD) {
        int o = (idx / CPAD) * 113 + idx % CPAD;
        float s = (part[0][o] + part[1][o]) + (part[2][o] + part[3][o]);
        if (p == 0) sA[q] = s;
        else if (p == 1) sA[q] += s;
        else if (p == 2) sB[q] = s;
        else sB[q] += s;
      }
    }
    __syncthreads();                    // phase reads done before next overwrite
  }

  // part fully consumed -> Pbuf may alias it
#pragma unroll
  for (int q = 0; q < 4; q++) {
    int idx = t + q * 1024;
    if (idx < 32 * CPAD) {
      int row = idx / CPAD, col = idx % CPAD;
      float P;
      if (it == 0) { Plab[(size_t)(r0 + row) * CPAD + col] = sA[q]; P = sA[q] + sB[q]; }
      else         { P = sA[q] + sB[q] + pl_pre[q]; }
      Pbuf[row * 114 + col] = P;
    }
  }
  __syncthreads();

  // ---- fused epilogue: wave w handles rows 2w, 2w+1 ----
  bool act = lane < 56;
  float dtot = 0.f;
#pragma unroll
  for (int rr = 0; rr < 2; rr++) {
    int rw = w * 2 + rr;
    int gr = r0 + rw;
    float2 p = make_float2(0.f, 0.f);
    if (act) p = *(const float2*)&Pbuf[rw * 114 + lane * 2];
    float2 xn;
    xn.x = xo[rr].x * p.x;
    xn.y = xo[rr].y * p.y;
    float s = xn.x + xn.y;
#pragma unroll
    for (int d = 1; d < 64; d <<= 1) s += __shfl_xor(s, d);
    float inv = 1.0f / s;
    float ent = 0.f, dsq = 0.f;
    if (act) {
      xn.x *= inv; xn.y *= inv;
      ent = -(xn.x * log2f(xn.x + 1e-20f) + xn.y * log2f(xn.y + 1e-20f));
      float dx = xn.x - xo[rr].x, dy = xn.y - xo[rr].y;
      dsq = dx * dx + dy * dy;
      *(float2*)(Xu + (size_t)gr * CPAD + lane * 2) = xn;
      int c0 = lane * 2;
      xbuf[c0 * 34 + rw]       = f2bf(xn.x);   // [c][34] stride: mild bank alias
      xbuf[(c0 + 1) * 34 + rw] = f2bf(xn.y);
    }
#pragma unroll
    for (int d = 1; d < 64; d <<= 1) { ent += __shfl_xor(ent, d); dsq += __shfl_xor(dsq, d); }
    if (lane == 0) hist[gr] += ent;
    dtot += dsq;
  }
  if (lane == 0) dsqb[w] = dtot;
  __syncthreads();

  // ---- coalesced X^T write-back: 16 threads x ushort2 = 32-elem run per col ----
#pragma unroll
  for (int q = 0; q < 2; q++) {
    int tt = t + q * 1024;
    if (tt < CPAD * 16) {
      int c = tt >> 4, jl = (tt & 15) * 2;
      ushort2 v = *(const ushort2*)&xbuf[c * 34 + jl];
      *(ushort2*)(XTw + (size_t)c * BROWS + NLAB + r0 + jl) = v;
    }
  }
  if (t == 0) {
    float ds = 0.f;
#pragma unroll
    for (int i = 0; i < 16; i++) ds += dsqb[i];
    atomicAdd(&errsq[it], ds);
  }
}

__global__ __launch_bounds__(256) void k_final(const float* __restrict__ hist,
                                               float* __restrict__ out) {
  int i = blockIdx.x * 256 + threadIdx.x;
  float yt = (i < NLAB) ? 0.0f : hist[i - NLAB] * (1.0f / 30.0f);
  out[BROWS + i] = yt;
  out[2 * BROWS + i] = (i < NLAB) ? 1.0f : 0.0f;
}

// ---------------------------------------------------------------------------
extern "C" void kernel_launch(void* const* d_in, const int* in_sizes, int n_in,
                              void* d_out, int out_size, void* d_ws, size_t ws_size,
                              hipStream_t stream) {
  const float* emb    = (const float*)d_in[1];
  const int*   labels = (const int*)d_in[2];
  const float* W1 = (const float*)d_in[3];
  const float* b1 = (const float*)d_in[4];
  const float* W2 = (const float*)d_in[5];
  const float* b2 = (const float*)d_in[6];
  const float* W3 = (const float*)d_in[7];
  const float* b3 = (const float*)d_in[8];
  const float* Wc = (const float*)d_in[9];
  const float* bc = (const float*)d_in[10];
  float* out = (float*)d_out;

  char* ws = (char*)d_ws;
  ushort* S    = (ushort*)(ws + OFF_S);
  ushort* Au   = (ushort*)(ws + OFF_AU);
  ushort* Eb   = (ushort*)(ws + OFF_EB);
  ushort* XT0  = (ushort*)(ws + OFF_XT0);
  ushort* XT1  = (ushort*)(ws + OFF_XT1);
  float*  Xu   = (float*)(ws + OFF_XU);
  float*  Plab = (float*)(ws + OFF_PL);
  float*  hist = (float*)(ws + OFF_HIST);
  float*  errs = (float*)(ws + OFF_ERR);
  double* ms   = (double*)(ws + OFF_MS);
  float*  rn   = (float*)(ws + OFF_RN);

  // zero hist + errsq + mean accumulator
  hipMemsetAsync(ws + OFF_HIST, 0, MEMSET_LEN, stream);

  k_prep<<<BROWS, 64, 0, stream>>>(emb, Eb, rn);
  k_mlp<<<BROWS / 16, 256, 0, stream>>>(emb, W1, b1, W2, b2, W3, b3, Wc, bc, out);

  { dim3 g(BROWS / 128, BROWS / 128); k_simM<<<g, 256, 0, stream>>>(Eb, rn, S, ms); }

  // overlay init (Eb dead now)
  { dim3 g(BROWS / 256, CPAD); k_initX<<<g, 256, 0, stream>>>(XT0, XT1, Xu, labels); }

  for (int it = 0; it < MAXIT; it++) {
    const ushort* XTr = (it & 1) ? XT1 : XT0;
    ushort*       XTw = (it & 1) ? XT0 : XT1;
    k_iter<<<NUNL / 32, 1024, 0, stream>>>(S, Au, XTr, XTw, Xu, Plab, hist, errs, ms, it);
  }

  k_final<<<BROWS / 256, 256, 0, stream>>>(hist, out);
}

// Round 4
// 779.416 us; speedup vs baseline: 2.0805x; 1.0258x over previous
//
#include <hip/hip_runtime.h>
#include <hip/hip_bf16.h>
#include <math.h>

// ---------------------------------------------------------------------------
// Problem constants
// ---------------------------------------------------------------------------
namespace {
constexpr int BROWS = 8192;
constexpr int NLAB  = 4096;
constexpr int NUNL  = 4096;
constexpr int CREAL = 100;
constexpr int CPAD  = 112;    // 7 mfma col-tiles of 16
constexpr int DIM   = 512;
constexpr int MAXIT = 30;

constexpr size_t MiB = 1ull << 20;
// ws layout (bytes).
constexpr size_t OFF_S    = 0;              // ushort[4096][8192] raw S  64 MiB (dead after it0)
constexpr size_t OFF_AU   = 64 * MiB;       // ushort[4096][4096] thresholded A (unlabeled K) 32 MiB
constexpr size_t OFF_EB   = 96 * MiB;       // ushort[8192][512] emb bf16 (dead after simM) 8 MiB
// overlay of EB after simM:
constexpr size_t OFF_XT0  = 96 * MiB;       // ushort[112][8192] X^T ping 1.75 MiB
constexpr size_t OFF_XT1  = 98 * MiB;       // X^T pong
constexpr size_t OFF_XU   = 100 * MiB;      // float[4096][112] exact X (unlabeled)
constexpr size_t OFF_PL   = 102 * MiB;      // float[4096][112] P_lab (static after it0)
// tail (never overlaid):
constexpr size_t OFF_HIST = 104 * MiB;          // float[4096]
constexpr size_t OFF_ERR  = 104 * MiB + 16384;  // float[32]
constexpr size_t OFF_MS   = 104 * MiB + 16768;  // double
constexpr size_t OFF_RN   = 104 * MiB + 32768;  // float[8192]
constexpr size_t MEMSET_LEN = 20480;            // HIST..MS inclusive
}

typedef __attribute__((ext_vector_type(8))) short short8;
typedef __attribute__((ext_vector_type(4))) float floatx4;

__device__ inline ushort f2bf(float f) {
  __hip_bfloat16 h = __float2bfloat16(f);
  union { __hip_bfloat16 b; ushort u; } c; c.b = h; return c.u;
}
__device__ inline float bf2f(ushort u) {
  union { ushort u; __hip_bfloat16 b; } c; c.u = u;
  return __bfloat162float(c.b);
}
// Non-temporal 16B load: identical value, no L2 allocation (streaming data).
__device__ inline short8 ntload_s8(const ushort* p) {
  return __builtin_nontemporal_load((const short8*)p);
}

// ---------------------------------------------------------------------------
// Fused: row 1/norm + emb fp32 -> bf16 cast.  One block per row, 64 lanes.
// ---------------------------------------------------------------------------
__global__ __launch_bounds__(64) void k_prep(const float* __restrict__ emb,
                                             ushort* __restrict__ Eb,
                                             float* __restrict__ rn) {
  int row = blockIdx.x, l = threadIdx.x;
  const float4* e4 = (const float4*)(emb + (size_t)row * DIM);
  float4 a = e4[2 * l], b = e4[2 * l + 1];
  float f[8] = {a.x, a.y, a.z, a.w, b.x, b.y, b.z, b.w};
  float s = 0.f;
#pragma unroll
  for (int q = 0; q < 8; q++) s += f[q] * f[q];
#pragma unroll
  for (int m = 1; m < 64; m <<= 1) s += __shfl_xor(s, m);
  if (l == 0) rn[row] = 1.0f / fmaxf(sqrtf(s), 1e-12f);
  union { short8 v; ushort u[8]; } o;
#pragma unroll
  for (int q = 0; q < 8; q++) o.u[q] = f2bf(f[q]);
  *(short8*)(Eb + (size_t)row * DIM + l * 8) = o.v;
}

// ---------------------------------------------------------------------------
// X init: bf16 X^T in both ping-pong buffers + exact fp32 unlabeled X
// ---------------------------------------------------------------------------
__global__ __launch_bounds__(256) void k_initX(ushort* __restrict__ X0,
                                               ushort* __restrict__ X1,
                                               float* __restrict__ Xu,
                                               const int* __restrict__ labels) {
  int j = blockIdx.x * 256 + threadIdx.x;       // 0..8191
  int c = blockIdx.y;                            // 0..111
  float v;
  if (j < NLAB) v = (labels[j] == c) ? 1.0f : 0.0f;
  else          v = (c < CREAL) ? 0.01f : 0.0f;
  ushort b = f2bf(v);
  X0[(size_t)c * BROWS + j] = b;
  X1[(size_t)c * BROWS + j] = b;
  if (j >= NLAB) Xu[(size_t)(j - NLAB) * CPAD + c] = (c < CREAL) ? 0.01f : 0.0f;
}

// ---------------------------------------------------------------------------
// MLP 512->256->128->64->1 (verified 4-row version; 15 KB LDS -> 8 blocks/CU
// = 32 waves/CU.  16-row variant regressed to 100 us via occupancy collapse
// [round 3 counters: 22.5% occ, VALUBusy 45%] -- do not re-block without
// keeping >=16 waves/CU.)
// ---------------------------------------------------------------------------
__global__ __launch_bounds__(256) void k_mlp(const float* __restrict__ emb,
                                             const float* __restrict__ W1, const float* __restrict__ b1,
                                             const float* __restrict__ W2, const float* __restrict__ b2,
                                             const float* __restrict__ W3, const float* __restrict__ b3,
                                             const float* __restrict__ Wc, const float* __restrict__ bc,
                                             float* __restrict__ out) {
  __shared__ float xs[4][512];
  __shared__ float h1[4][256];
  __shared__ float h2[4][128];
  __shared__ float h3[4][64];
  int t = threadIdx.x;
  int r0 = blockIdx.x * 4;
  {
    const float4* src = (const float4*)(emb + (size_t)r0 * DIM);
    float4* dst = (float4*)&xs[0][0];
    dst[t] = src[t];
    dst[t + 256] = src[t + 256];
  }
  __syncthreads();
  {
    float a0 = 0.f, a1 = 0.f, a2 = 0.f, a3 = 0.f;
    for (int k = 0; k < 512; k++) {
      float w = W1[k * 256 + t];
      a0 = fmaf(xs[0][k], w, a0);
      a1 = fmaf(xs[1][k], w, a1);
      a2 = fmaf(xs[2][k], w, a2);
      a3 = fmaf(xs[3][k], w, a3);
    }
    float bb = b1[t];
    h1[0][t] = fmaxf(a0 + bb, 0.f);
    h1[1][t] = fmaxf(a1 + bb, 0.f);
    h1[2][t] = fmaxf(a2 + bb, 0.f);
    h1[3][t] = fmaxf(a3 + bb, 0.f);
  }
  __syncthreads();
  {
    int c = t & 127, rb = (t >> 7) * 2;
    float a0 = 0.f, a1 = 0.f;
    for (int k = 0; k < 256; k++) {
      float w = W2[k * 128 + c];
      a0 = fmaf(h1[rb][k], w, a0);
      a1 = fmaf(h1[rb + 1][k], w, a1);
    }
    float bb = b2[c];
    h2[rb][c] = fmaxf(a0 + bb, 0.f);
    h2[rb + 1][c] = fmaxf(a1 + bb, 0.f);
  }
  __syncthreads();
  {
    int c = t & 63, r = t >> 6;
    float a = 0.f;
    for (int k = 0; k < 128; k++) a = fmaf(h2[r][k], W3[k * 64 + c], a);
    h3[r][c] = fmaxf(a + b3[c], 0.f);
  }
  __syncthreads();
  {
    int r = t >> 6, l = t & 63;
    float v = h3[r][l] * Wc[l];
#pragma unroll
    for (int m = 32; m; m >>= 1) v += __shfl_down(v, m);
    if (l == 0) out[r0 + r] = v + bc[0];
  }
}

// ---------------------------------------------------------------------------
// Similarity (proven 93-95 us, unchanged).
// ---------------------------------------------------------------------------
__global__ __launch_bounds__(256) void k_simM(const ushort* __restrict__ Eb,
                                              const float* __restrict__ rn,
                                              ushort* __restrict__ S,
                                              double* __restrict__ meansum) {
  int x = blockIdx.x, y = blockIdx.y;
  if (x < 32 && y > x) return;
  __shared__ ushort Ei[128 * 40];
  __shared__ ushort Ej[128 * 40];
  __shared__ float redbuf[4];

  int t = threadIdx.x;
  int w = t >> 6, lane = t & 63;
  int m = lane & 15, g = lane >> 4;
  int ib = (w >> 1) * 64, jb = (w & 1) * 64;
  int i0 = x * 128, j0 = y * 128;

  floatx4 acc[4][4];
#pragma unroll
  for (int a = 0; a < 4; a++)
#pragma unroll
    for (int b = 0; b < 4; b++) acc[a][b] = (floatx4)0.0f;

  int lrow = t >> 1, lhalf = (t & 1) * 16;
  for (int kt = 0; kt < DIM; kt += 32) {
    __syncthreads();
    {
      const ushort* gi = Eb + (size_t)(i0 + lrow) * DIM + kt + lhalf;
      const ushort* gj = Eb + (size_t)(j0 + lrow) * DIM + kt + lhalf;
      int o = lrow * 40 + lhalf;
      *(short8*)&Ei[o]     = *(const short8*)gi;
      *(short8*)&Ei[o + 8] = *(const short8*)(gi + 8);
      *(short8*)&Ej[o]     = *(const short8*)gj;
      *(short8*)&Ej[o + 8] = *(const short8*)(gj + 8);
    }
    __syncthreads();

    short8 ah[4], bh[4];
#pragma unroll
    for (int rt = 0; rt < 4; rt++) ah[rt] = *(const short8*)&Ei[(ib + rt * 16 + m) * 40 + g * 8];
#pragma unroll
    for (int ct = 0; ct < 4; ct++) bh[ct] = *(const short8*)&Ej[(jb + ct * 16 + m) * 40 + g * 8];
#pragma unroll
    for (int rt = 0; rt < 4; rt++)
#pragma unroll
      for (int ct = 0; ct < 4; ct++)
        acc[rt][ct] = __builtin_amdgcn_mfma_f32_16x16x32_bf16(ah[rt], bh[ct], acc[rt][ct], 0, 0, 0);
  }

  bool dostore = (x >= 32);
  bool isdiag  = (x == y);
  float weight = (x < 32) ? (isdiag ? 1.0f : 2.0f) : ((y < 32) ? 2.0f : 1.0f);
  float lsum = 0.f;
#pragma unroll
  for (int rt = 0; rt < 4; rt++) {
    int gi0 = i0 + ib + rt * 16 + g * 4;
    float4 rni = *(const float4*)(rn + gi0);
#pragma unroll
    for (int ct = 0; ct < 4; ct++) {
      int gj = j0 + jb + ct * 16 + m;
      float rnj = rn[gj];
#pragma unroll
      for (int r = 0; r < 4; r++) {
        int gi = gi0 + r;
        float rv = (r == 0) ? rni.x : (r == 1) ? rni.y : (r == 2) ? rni.z : rni.w;
        float s = acc[rt][ct][r] * rv * rnj;
        if (isdiag && gi == gj) s = 0.f;
        s = fminf(fmaxf(s, 0.f), 1.f);
        lsum += s;
        if (dostore) S[(size_t)(gi - NLAB) * BROWS + gj] = f2bf(s);
      }
    }
  }
  lsum *= weight;
#pragma unroll
  for (int d = 1; d < 64; d <<= 1) lsum += __shfl_xor(lsum, d);
  if (lane == 0) redbuf[w] = lsum;
  __syncthreads();
  if (t == 0) atomicAdd(meansum, (double)(redbuf[0] + redbuf[1] + redbuf[2] + redbuf[3]));
}

// ---------------------------------------------------------------------------
// One replicator iteration (proven 16-row / grid-256 structure).
// NEW this round: S-loads (it0) and Au-loads (it>0) are NON-TEMPORAL.
// Rationale: per-XCD L2 working set = XT panel (896 KB, shared by the 32
// blocks on the XCD) + 32 x 128 KB private Au slices = 4.9 MB > 4 MB L2.
// Au/S are zero-reuse streams; nt keeps them from evicting the shared panel.
// Values are bit-identical (only cache allocation changes).
// ---------------------------------------------------------------------------
__global__ __launch_bounds__(1024, 4) void k_iter(const ushort* __restrict__ S,
                                                  ushort* __restrict__ Au,
                                                  const ushort* __restrict__ XTr,
                                                  ushort* __restrict__ XTw,
                                                  float* __restrict__ Xu,
                                                  float* __restrict__ Plab,
                                                  float* __restrict__ hist,
                                                  float* __restrict__ errsq,
                                                  const double* __restrict__ ms,
                                                  int it) {
  if (it > 0 && errsq[it - 1] <= 1e-6f) return;
  __shared__ float part[8][16 * 113];   // 57856 B (reused as xbuf after last read)
  __shared__ float Pbuf[16 * 114];      //  7296 B
  __shared__ float dsqbuf[16];
  ushort* xbuf = (ushort*)&part[0][0];  // [112][18] ushort transpose stage (4032 B)
  int t = threadIdx.x;
  int w = t >> 6, lane = t & 63;
  int m = lane & 15, g = lane >> 4;
  int r0 = blockIdx.x * 16;             // unlabeled row base (i' space)

  // ---- entry prefetches (latency hidden behind GEMM phase) ----
  float2 xo = make_float2(0.f, 0.f);
  if (lane < 56) xo = *(const float2*)(Xu + (size_t)(r0 + w) * CPAD + lane * 2);
  float pl_pre[2] = {0.f, 0.f};
  if (it > 0) {
#pragma unroll
    for (int q = 0; q < 2; q++) {
      int idx = t + q * 1024;
      if (idx < 16 * CPAD)
        pl_pre[q] = Plab[(size_t)(r0 + idx / CPAD) * CPAD + idx % CPAD];
    }
  }

  floatx4 acc[7];
#pragma unroll
  for (int c = 0; c < 7; c++) acc[c] = (floatx4)0.0f;

  if (it == 0) {
    float mean = (float)(ms[0] * (1.0 / ((double)BROWS * (double)BROWS)));
    int kw = w * 512;                   // wave w: k in [w*512, w*512+512)
    for (int ks = 0; ks < 16; ks++) {
      int kk = kw + ks * 32;
      size_t so = (size_t)(r0 + m) * BROWS + kk + g * 8;
      short8 a = ntload_s8(S + so);     // streaming: don't allocate in L2
      union { short8 v; ushort u[8]; } ua; ua.v = a;
#pragma unroll
      for (int e = 0; e < 8; e++) {
        float s = bf2f(ua.u[e]);
        float av = (s < mean) ? 1.0f : 1.0f - s;
        ua.u[e] = f2bf(av);
      }
      a = ua.v;
      if (w >= 8)   // unlabeled K half -> persist for it>0
        *(short8*)(Au + (size_t)(r0 + m) * NUNL + (kk - NLAB) + g * 8) = a;
#pragma unroll
      for (int ct = 0; ct < 7; ct++) {
        short8 b = *(const short8*)(XTr + (size_t)(ct * 16 + m) * BROWS + kk + g * 8);
        acc[ct] = __builtin_amdgcn_mfma_f32_16x16x32_bf16(a, b, acc[ct], 0, 0, 0);
      }
    }
  } else {
    int kw = w * 256;                   // Au-relative: wave w k in [w*256,+256)
    size_t abase = (size_t)(r0 + m) * NUNL + kw + g * 8;
    size_t bbase = (size_t)m * BROWS + NLAB + kw + g * 8;
    for (int ks = 0; ks < 8; ks++) {
      short8 a = ntload_s8(Au + abase + ks * 32);   // streaming: protect XT panel in L2
#pragma unroll
      for (int ct = 0; ct < 7; ct++) {
        short8 b = *(const short8*)(XTr + bbase + (size_t)ct * 16 * BROWS + ks * 32);
        acc[ct] = __builtin_amdgcn_mfma_f32_16x16x32_bf16(a, b, acc[ct], 0, 0, 0);
      }
    }
  }

  // ---- two-phase reduction of 16 wave-partials through 8 LDS buffers ----
  // (D-frag map: row = g*4+r, col = ct*16+m)
  if (w < 8) {
#pragma unroll
    for (int ct = 0; ct < 7; ct++)
#pragma unroll
      for (int r = 0; r < 4; r++)
        part[w][(g * 4 + r) * 113 + ct * 16 + m] = acc[ct][r];
  }
  __syncthreads();
  float sA[2] = {0.f, 0.f}, sB[2] = {0.f, 0.f};
#pragma unroll
  for (int q = 0; q < 2; q++) {
    int idx = t + q * 1024;
    if (idx < 16 * CPAD) {
      int row = idx / CPAD, col = idx % CPAD;
      int o = row * 113 + col;
      sA[q] = ((part[0][o] + part[1][o]) + (part[2][o] + part[3][o]))
            + ((part[4][o] + part[5][o]) + (part[6][o] + part[7][o]));
    }
  }
  __syncthreads();
  if (w >= 8) {
#pragma unroll
    for (int ct = 0; ct < 7; ct++)
#pragma unroll
      for (int r = 0; r < 4; r++)
        part[w - 8][(g * 4 + r) * 113 + ct * 16 + m] = acc[ct][r];
  }
  __syncthreads();
#pragma unroll
  for (int q = 0; q < 2; q++) {
    int idx = t + q * 1024;
    if (idx < 16 * CPAD) {
      int row = idx / CPAD, col = idx % CPAD;
      int o = row * 113 + col;
      sB[q] = ((part[0][o] + part[1][o]) + (part[2][o] + part[3][o]))
            + ((part[4][o] + part[5][o]) + (part[6][o] + part[7][o]));
      float P;
      size_t go = (size_t)(r0 + row) * CPAD + col;
      if (it == 0) { Plab[go] = sA[q]; P = sA[q] + sB[q]; }  // waves 0-7 = labeled K
      else         { P = sA[q] + sB[q] + pl_pre[q]; }
      Pbuf[row * 114 + col] = P;
    }
  }
  __syncthreads();                      // part reads done -> xbuf may alias it

  // ---- fused epilogue: wave w handles row w ----
  int gr = r0 + w;
  bool act = lane < 56;
  float2 p = make_float2(0.f, 0.f);
  if (act) p = *(const float2*)&Pbuf[w * 114 + lane * 2];
  float2 xn;
  xn.x = xo.x * p.x;
  xn.y = xo.y * p.y;
  float s = xn.x + xn.y;
#pragma unroll
  for (int d = 1; d < 64; d <<= 1) s += __shfl_xor(s, d);
  float inv = 1.0f / s;
  float ent = 0.f, dsq = 0.f;
  if (act) {
    xn.x *= inv; xn.y *= inv;
    ent = -(xn.x * log2f(xn.x + 1e-20f) + xn.y * log2f(xn.y + 1e-20f));
    float dx = xn.x - xo.x, dy = xn.y - xo.y;
    dsq = dx * dx + dy * dy;
    *(float2*)(Xu + (size_t)gr * CPAD + lane * 2) = xn;
    int c0 = lane * 2;
    xbuf[c0 * 18 + w]       = f2bf(xn.x);   // [c][18] stride: 2-way max bank alias
    xbuf[(c0 + 1) * 18 + w] = f2bf(xn.y);
  }
#pragma unroll
  for (int d = 1; d < 64; d <<= 1) { ent += __shfl_xor(ent, d); dsq += __shfl_xor(dsq, d); }
  if (lane == 0) {
    hist[gr] += ent;
    dsqbuf[w] = dsq;
  }
  __syncthreads();

  // ---- coalesced X^T write-back: 8 threads x ushort2 = 32B run per column ----
  if (t < CPAD * 8) {
    int c = t >> 3, jl = (t & 7) * 2;
    ushort2 v = *(const ushort2*)&xbuf[c * 18 + jl];
    *(ushort2*)(XTw + (size_t)c * BROWS + NLAB + r0 + jl) = v;
  }
  if (t == 0) {
    float ds = 0.f;
#pragma unroll
    for (int i = 0; i < 16; i++) ds += dsqbuf[i];
    atomicAdd(&errsq[it], ds);
  }
}

__global__ __launch_bounds__(256) void k_final(const float* __restrict__ hist,
                                               float* __restrict__ out) {
  int i = blockIdx.x * 256 + threadIdx.x;
  float yt = (i < NLAB) ? 0.0f : hist[i - NLAB] * (1.0f / 30.0f);
  out[BROWS + i] = yt;
  out[2 * BROWS + i] = (i < NLAB) ? 1.0f : 0.0f;
}

// ---------------------------------------------------------------------------
extern "C" void kernel_launch(void* const* d_in, const int* in_sizes, int n_in,
                              void* d_out, int out_size, void* d_ws, size_t ws_size,
                              hipStream_t stream) {
  const float* emb    = (const float*)d_in[1];
  const int*   labels = (const int*)d_in[2];
  const float* W1 = (const float*)d_in[3];
  const float* b1 = (const float*)d_in[4];
  const float* W2 = (const float*)d_in[5];
  const float* b2 = (const float*)d_in[6];
  const float* W3 = (const float*)d_in[7];
  const float* b3 = (const float*)d_in[8];
  const float* Wc = (const float*)d_in[9];
  const float* bc = (const float*)d_in[10];
  float* out = (float*)d_out;

  char* ws = (char*)d_ws;
  ushort* S    = (ushort*)(ws + OFF_S);
  ushort* Au   = (ushort*)(ws + OFF_AU);
  ushort* Eb   = (ushort*)(ws + OFF_EB);
  ushort* XT0  = (ushort*)(ws + OFF_XT0);
  ushort* XT1  = (ushort*)(ws + OFF_XT1);
  float*  Xu   = (float*)(ws + OFF_XU);
  float*  Plab = (float*)(ws + OFF_PL);
  float*  hist = (float*)(ws + OFF_HIST);
  float*  errs = (float*)(ws + OFF_ERR);
  double* ms   = (double*)(ws + OFF_MS);
  float*  rn   = (float*)(ws + OFF_RN);

  // zero hist + errsq + mean accumulator
  hipMemsetAsync(ws + OFF_HIST, 0, MEMSET_LEN, stream);

  k_prep<<<BROWS, 64, 0, stream>>>(emb, Eb, rn);
  k_mlp<<<BROWS / 4, 256, 0, stream>>>(emb, W1, b1, W2, b2, W3, b3, Wc, bc, out);

  { dim3 g(BROWS / 128, BROWS / 128); k_simM<<<g, 256, 0, stream>>>(Eb, rn, S, ms); }

  // overlay init (Eb dead now)
  { dim3 g(BROWS / 256, CPAD); k_initX<<<g, 256, 0, stream>>>(XT0, XT1, Xu, labels); }

  for (int it = 0; it < MAXIT; it++) {
    const ushort* XTr = (it & 1) ? XT1 : XT0;
    ushort*       XTw = (it & 1) ? XT0 : XT1;
    k_iter<<<NUNL / 16, 1024, 0, stream>>>(S, Au, XTr, XTw, Xu, Plab, hist, errs, ms, it);
  }

  k_final<<<BROWS / 256, 256, 0, stream>>>(hist, out);
}

// Round 5
// 726.851 us; speedup vs baseline: 2.2310x; 1.0723x over previous
//
#include <hip/hip_runtime.h>
#include <hip/hip_bf16.h>
#include <math.h>

// ---------------------------------------------------------------------------
// Problem constants
// ---------------------------------------------------------------------------
namespace {
constexpr int BROWS = 8192;
constexpr int NLAB  = 4096;
constexpr int NUNL  = 4096;
constexpr int CREAL = 100;
constexpr int CPAD  = 112;    // 7 mfma col-tiles of 16
constexpr int DIM   = 512;
constexpr int MAXIT = 30;

constexpr size_t MiB = 1ull << 20;
// ws layout (bytes).
constexpr size_t OFF_S    = 0;              // ushort[4096][8192] raw S  64 MiB (dead after it0)
constexpr size_t OFF_AU   = 64 * MiB;       // ushort[4096][4096] thresholded A (unlabeled K) 32 MiB
constexpr size_t OFF_EB   = 96 * MiB;       // ushort[8192][512] emb bf16 (dead after simM) 8 MiB
// overlay of EB after simM:
constexpr size_t OFF_XT0  = 96 * MiB;       // ushort[112][8192] X^T ping 1.75 MiB
constexpr size_t OFF_XT1  = 98 * MiB;       // X^T pong
constexpr size_t OFF_XU   = 100 * MiB;      // float[4096][112] exact X (unlabeled)
constexpr size_t OFF_PL   = 102 * MiB;      // float[4096][112] P_lab (static after it0)
// tail (never overlaid):
constexpr size_t OFF_HIST = 104 * MiB;          // float[4096]
constexpr size_t OFF_ERR  = 104 * MiB + 16384;  // float[32]
constexpr size_t OFF_MS   = 104 * MiB + 16768;  // double
constexpr size_t OFF_RN   = 104 * MiB + 32768;  // float[8192]
constexpr size_t MEMSET_LEN = 20480;            // HIST..MS inclusive

// k_iter dynamic LDS: part16 115712 + Pbuf 7296 + dsqb 64 = 123072 B
constexpr unsigned ITER_DLDS = 123072u;
}

typedef __attribute__((ext_vector_type(8))) short short8;
typedef __attribute__((ext_vector_type(4))) float floatx4;

__device__ inline ushort f2bf(float f) {
  __hip_bfloat16 h = __float2bfloat16(f);
  union { __hip_bfloat16 b; ushort u; } c; c.b = h; return c.u;
}
__device__ inline float bf2f(ushort u) {
  union { ushort u; __hip_bfloat16 b; } c; c.u = u;
  return __bfloat162float(c.b);
}

// ---------------------------------------------------------------------------
// Fused: row 1/norm + emb fp32 -> bf16 cast.  One block per row, 64 lanes.
// ---------------------------------------------------------------------------
__global__ __launch_bounds__(64) void k_prep(const float* __restrict__ emb,
                                             ushort* __restrict__ Eb,
                                             float* __restrict__ rn) {
  int row = blockIdx.x, l = threadIdx.x;
  const float4* e4 = (const float4*)(emb + (size_t)row * DIM);
  float4 a = e4[2 * l], b = e4[2 * l + 1];
  float f[8] = {a.x, a.y, a.z, a.w, b.x, b.y, b.z, b.w};
  float s = 0.f;
#pragma unroll
  for (int q = 0; q < 8; q++) s += f[q] * f[q];
#pragma unroll
  for (int m = 1; m < 64; m <<= 1) s += __shfl_xor(s, m);
  if (l == 0) rn[row] = 1.0f / fmaxf(sqrtf(s), 1e-12f);
  union { short8 v; ushort u[8]; } o;
#pragma unroll
  for (int q = 0; q < 8; q++) o.u[q] = f2bf(f[q]);
  *(short8*)(Eb + (size_t)row * DIM + l * 8) = o.v;
}

// ---------------------------------------------------------------------------
// X init: bf16 X^T in both ping-pong buffers + exact fp32 unlabeled X
// ---------------------------------------------------------------------------
__global__ __launch_bounds__(256) void k_initX(ushort* __restrict__ X0,
                                               ushort* __restrict__ X1,
                                               float* __restrict__ Xu,
                                               const int* __restrict__ labels) {
  int j = blockIdx.x * 256 + threadIdx.x;       // 0..8191
  int c = blockIdx.y;                            // 0..111
  float v;
  if (j < NLAB) v = (labels[j] == c) ? 1.0f : 0.0f;
  else          v = (c < CREAL) ? 0.01f : 0.0f;
  ushort b = f2bf(v);
  X0[(size_t)c * BROWS + j] = b;
  X1[(size_t)c * BROWS + j] = b;
  if (j >= NLAB) Xu[(size_t)(j - NLAB) * CPAD + c] = (c < CREAL) ? 0.01f : 0.0f;
}

// ---------------------------------------------------------------------------
// MLP 512->256->128->64->1 (verified 4-row; 15 KB LDS -> 8 blocks/CU = full
// occupancy.  16-row variant regressed to ~100 us via occupancy collapse
// [round-3 counters: 22.5% occ] -- do not re-block without >=16 waves/CU.)
// ---------------------------------------------------------------------------
__global__ __launch_bounds__(256) void k_mlp(const float* __restrict__ emb,
                                             const float* __restrict__ W1, const float* __restrict__ b1,
                                             const float* __restrict__ W2, const float* __restrict__ b2,
                                             const float* __restrict__ W3, const float* __restrict__ b3,
                                             const float* __restrict__ Wc, const float* __restrict__ bc,
                                             float* __restrict__ out) {
  __shared__ float xs[4][512];
  __shared__ float h1[4][256];
  __shared__ float h2[4][128];
  __shared__ float h3[4][64];
  int t = threadIdx.x;
  int r0 = blockIdx.x * 4;
  {
    const float4* src = (const float4*)(emb + (size_t)r0 * DIM);
    float4* dst = (float4*)&xs[0][0];
    dst[t] = src[t];
    dst[t + 256] = src[t + 256];
  }
  __syncthreads();
  {
    float a0 = 0.f, a1 = 0.f, a2 = 0.f, a3 = 0.f;
    for (int k = 0; k < 512; k++) {
      float w = W1[k * 256 + t];
      a0 = fmaf(xs[0][k], w, a0);
      a1 = fmaf(xs[1][k], w, a1);
      a2 = fmaf(xs[2][k], w, a2);
      a3 = fmaf(xs[3][k], w, a3);
    }
    float bb = b1[t];
    h1[0][t] = fmaxf(a0 + bb, 0.f);
    h1[1][t] = fmaxf(a1 + bb, 0.f);
    h1[2][t] = fmaxf(a2 + bb, 0.f);
    h1[3][t] = fmaxf(a3 + bb, 0.f);
  }
  __syncthreads();
  {
    int c = t & 127, rb = (t >> 7) * 2;
    float a0 = 0.f, a1 = 0.f;
    for (int k = 0; k < 256; k++) {
      float w = W2[k * 128 + c];
      a0 = fmaf(h1[rb][k], w, a0);
      a1 = fmaf(h1[rb + 1][k], w, a1);
    }
    float bb = b2[c];
    h2[rb][c] = fmaxf(a0 + bb, 0.f);
    h2[rb + 1][c] = fmaxf(a1 + bb, 0.f);
  }
  __syncthreads();
  {
    int c = t & 63, r = t >> 6;
    float a = 0.f;
    for (int k = 0; k < 128; k++) a = fmaf(h2[r][k], W3[k * 64 + c], a);
    h3[r][c] = fmaxf(a + b3[c], 0.f);
  }
  __syncthreads();
  {
    int r = t >> 6, l = t & 63;
    float v = h3[r][l] * Wc[l];
#pragma unroll
    for (int m = 32; m; m >>= 1) v += __shfl_down(v, m);
    if (l == 0) out[r0 + r] = v + bc[0];
  }
}

// ---------------------------------------------------------------------------
// Similarity (proven 93-97 us, unchanged).
// ---------------------------------------------------------------------------
__global__ __launch_bounds__(256) void k_simM(const ushort* __restrict__ Eb,
                                              const float* __restrict__ rn,
                                              ushort* __restrict__ S,
                                              double* __restrict__ meansum) {
  int x = blockIdx.x, y = blockIdx.y;
  if (x < 32 && y > x) return;
  __shared__ ushort Ei[128 * 40];
  __shared__ ushort Ej[128 * 40];
  __shared__ float redbuf[4];

  int t = threadIdx.x;
  int w = t >> 6, lane = t & 63;
  int m = lane & 15, g = lane >> 4;
  int ib = (w >> 1) * 64, jb = (w & 1) * 64;
  int i0 = x * 128, j0 = y * 128;

  floatx4 acc[4][4];
#pragma unroll
  for (int a = 0; a < 4; a++)
#pragma unroll
    for (int b = 0; b < 4; b++) acc[a][b] = (floatx4)0.0f;

  int lrow = t >> 1, lhalf = (t & 1) * 16;
  for (int kt = 0; kt < DIM; kt += 32) {
    __syncthreads();
    {
      const ushort* gi = Eb + (size_t)(i0 + lrow) * DIM + kt + lhalf;
      const ushort* gj = Eb + (size_t)(j0 + lrow) * DIM + kt + lhalf;
      int o = lrow * 40 + lhalf;
      *(short8*)&Ei[o]     = *(const short8*)gi;
      *(short8*)&Ei[o + 8] = *(const short8*)(gi + 8);
      *(short8*)&Ej[o]     = *(const short8*)gj;
      *(short8*)&Ej[o + 8] = *(const short8*)(gj + 8);
    }
    __syncthreads();

    short8 ah[4], bh[4];
#pragma unroll
    for (int rt = 0; rt < 4; rt++) ah[rt] = *(const short8*)&Ei[(ib + rt * 16 + m) * 40 + g * 8];
#pragma unroll
    for (int ct = 0; ct < 4; ct++) bh[ct] = *(const short8*)&Ej[(jb + ct * 16 + m) * 40 + g * 8];
#pragma unroll
    for (int rt = 0; rt < 4; rt++)
#pragma unroll
      for (int ct = 0; ct < 4; ct++)
        acc[rt][ct] = __builtin_amdgcn_mfma_f32_16x16x32_bf16(ah[rt], bh[ct], acc[rt][ct], 0, 0, 0);
  }

  bool dostore = (x >= 32);
  bool isdiag  = (x == y);
  float weight = (x < 32) ? (isdiag ? 1.0f : 2.0f) : ((y < 32) ? 2.0f : 1.0f);
  float lsum = 0.f;
#pragma unroll
  for (int rt = 0; rt < 4; rt++) {
    int gi0 = i0 + ib + rt * 16 + g * 4;
    float4 rni = *(const float4*)(rn + gi0);
#pragma unroll
    for (int ct = 0; ct < 4; ct++) {
      int gj = j0 + jb + ct * 16 + m;
      float rnj = rn[gj];
#pragma unroll
      for (int r = 0; r < 4; r++) {
        int gi = gi0 + r;
        float rv = (r == 0) ? rni.x : (r == 1) ? rni.y : (r == 2) ? rni.z : rni.w;
        float s = acc[rt][ct][r] * rv * rnj;
        if (isdiag && gi == gj) s = 0.f;
        s = fminf(fmaxf(s, 0.f), 1.f);
        lsum += s;
        if (dostore) S[(size_t)(gi - NLAB) * BROWS + gj] = f2bf(s);
      }
    }
  }
  lsum *= weight;
#pragma unroll
  for (int d = 1; d < 64; d <<= 1) lsum += __shfl_xor(lsum, d);
  if (lane == 0) redbuf[w] = lsum;
  __syncthreads();
  if (t == 0) atomicAdd(meansum, (double)(redbuf[0] + redbuf[1] + redbuf[2] + redbuf[3]));
}

// ---------------------------------------------------------------------------
// One replicator iteration (proven 16-row / grid-256 structure; PLAIN loads
// -- nt-loads on Au regressed ~2 us/iter in round 4: Au has cross-launch L2
// reuse because identical grids map blocks to the same CUs).
// NEW this round: single-phase reduction.  16 separate partial buffers in
// DYNAMIC LDS (123 KB, 1 block/CU -- grid 256 = CU count, so no occupancy
// loss) replace the two-phase / 8-buffer scheme: 3 barriers instead of 5,
// waves 8-15 no longer stall through phase 1.  Reduction tree preserved
// EXACTLY: sA = ((p0+p1)+(p2+p3))+((p4+p5)+(p6+p7)), sB = same over 8..15,
// P = (sA+sB)+pl -> bitwise-identical output.
// ---------------------------------------------------------------------------
__global__ __launch_bounds__(1024, 4) void k_iter(const ushort* __restrict__ S,
                                                  ushort* __restrict__ Au,
                                                  const ushort* __restrict__ XTr,
                                                  ushort* __restrict__ XTw,
                                                  float* __restrict__ Xu,
                                                  float* __restrict__ Plab,
                                                  float* __restrict__ hist,
                                                  float* __restrict__ errsq,
                                                  const double* __restrict__ ms,
                                                  int it) {
  if (it > 0 && errsq[it - 1] <= 1e-6f) return;
  extern __shared__ float lds[];
  float*  part = lds;                       // [16][1808] = 115712 B
  float*  Pbuf = lds + 28928;               // [16][114]  =   7296 B
  float*  dsqb = lds + 28928 + 1824;        // [16]
  ushort* xbuf = (ushort*)lds;              // [112][18] alias (part dead then)

  int t = threadIdx.x;
  int w = t >> 6, lane = t & 63;
  int m = lane & 15, g = lane >> 4;
  int r0 = blockIdx.x * 16;             // unlabeled row base (i' space)

  // ---- entry prefetches (latency hidden behind GEMM phase) ----
  float2 xo = make_float2(0.f, 0.f);
  if (lane < 56) xo = *(const float2*)(Xu + (size_t)(r0 + w) * CPAD + lane * 2);
  float pl_pre[2] = {0.f, 0.f};
  if (it > 0) {
#pragma unroll
    for (int q = 0; q < 2; q++) {
      int idx = t + q * 1024;
      if (idx < 16 * CPAD)
        pl_pre[q] = Plab[(size_t)(r0 + idx / CPAD) * CPAD + idx % CPAD];
    }
  }

  floatx4 acc[7];
#pragma unroll
  for (int c = 0; c < 7; c++) acc[c] = (floatx4)0.0f;

  if (it == 0) {
    float mean = (float)(ms[0] * (1.0 / ((double)BROWS * (double)BROWS)));
    int kw = w * 512;                   // wave w: k in [w*512, w*512+512)
    for (int ks = 0; ks < 16; ks++) {
      int kk = kw + ks * 32;
      size_t so = (size_t)(r0 + m) * BROWS + kk + g * 8;
      short8 a = *(const short8*)(S + so);
      union { short8 v; ushort u[8]; } ua; ua.v = a;
#pragma unroll
      for (int e = 0; e < 8; e++) {
        float s = bf2f(ua.u[e]);
        float av = (s < mean) ? 1.0f : 1.0f - s;
        ua.u[e] = f2bf(av);
      }
      a = ua.v;
      if (w >= 8)   // unlabeled K half -> persist for it>0
        *(short8*)(Au + (size_t)(r0 + m) * NUNL + (kk - NLAB) + g * 8) = a;
#pragma unroll
      for (int ct = 0; ct < 7; ct++) {
        short8 b = *(const short8*)(XTr + (size_t)(ct * 16 + m) * BROWS + kk + g * 8);
        acc[ct] = __builtin_amdgcn_mfma_f32_16x16x32_bf16(a, b, acc[ct], 0, 0, 0);
      }
    }
  } else {
    int kw = w * 256;                   // Au-relative: wave w k in [w*256,+256)
    size_t abase = (size_t)(r0 + m) * NUNL + kw + g * 8;
    size_t bbase = (size_t)m * BROWS + NLAB + kw + g * 8;
    for (int ks = 0; ks < 8; ks++) {
      short8 a = *(const short8*)(Au + abase + ks * 32);
#pragma unroll
      for (int ct = 0; ct < 7; ct++) {
        short8 b = *(const short8*)(XTr + bbase + (size_t)ct * 16 * BROWS + ks * 32);
        acc[ct] = __builtin_amdgcn_mfma_f32_16x16x32_bf16(a, b, acc[ct], 0, 0, 0);
      }
    }
  }

  // ---- single-phase reduction: all 16 wave-partials live at once ----
  // (D-frag map: row = g*4+r, col = ct*16+m)
#pragma unroll
  for (int ct = 0; ct < 7; ct++)
#pragma unroll
    for (int r = 0; r < 4; r++)
      part[w * 1808 + (g * 4 + r) * 113 + ct * 16 + m] = acc[ct][r];
  __syncthreads();
#pragma unroll
  for (int q = 0; q < 2; q++) {
    int idx = t + q * 1024;
    if (idx < 16 * CPAD) {
      int row = idx / CPAD, col = idx % CPAD;
      int o = row * 113 + col;
      float sA = ((part[o]           + part[1808 + o])   + (part[2 * 1808 + o]  + part[3 * 1808 + o]))
               + ((part[4 * 1808 + o] + part[5 * 1808 + o]) + (part[6 * 1808 + o] + part[7 * 1808 + o]));
      float sB = ((part[8 * 1808 + o] + part[9 * 1808 + o]) + (part[10 * 1808 + o] + part[11 * 1808 + o]))
               + ((part[12 * 1808 + o] + part[13 * 1808 + o]) + (part[14 * 1808 + o] + part[15 * 1808 + o]));
      float P;
      size_t go = (size_t)(r0 + row) * CPAD + col;
      if (it == 0) { Plab[go] = sA; P = sA + sB; }  // waves 0-7 = labeled K
      else         { P = sA + sB + pl_pre[q]; }
      Pbuf[row * 114 + col] = P;
    }
  }
  __syncthreads();                      // part reads done -> xbuf may alias it

  // ---- fused epilogue: wave w handles row w ----
  int gr = r0 + w;
  bool act = lane < 56;
  float2 p = make_float2(0.f, 0.f);
  if (act) p = *(const float2*)&Pbuf[w * 114 + lane * 2];
  float2 xn;
  xn.x = xo.x * p.x;
  xn.y = xo.y * p.y;
  float s = xn.x + xn.y;
#pragma unroll
  for (int d = 1; d < 64; d <<= 1) s += __shfl_xor(s, d);
  float inv = 1.0f / s;
  float ent = 0.f, dsq = 0.f;
  if (act) {
    xn.x *= inv; xn.y *= inv;
    ent = -(xn.x * log2f(xn.x + 1e-20f) + xn.y * log2f(xn.y + 1e-20f));
    float dx = xn.x - xo.x, dy = xn.y - xo.y;
    dsq = dx * dx + dy * dy;
    *(float2*)(Xu + (size_t)gr * CPAD + lane * 2) = xn;
    int c0 = lane * 2;
    xbuf[c0 * 18 + w]       = f2bf(xn.x);   // [c][18] stride: 2-way max bank alias
    xbuf[(c0 + 1) * 18 + w] = f2bf(xn.y);
  }
#pragma unroll
  for (int d = 1; d < 64; d <<= 1) { ent += __shfl_xor(ent, d); dsq += __shfl_xor(dsq, d); }
  if (lane == 0) {
    hist[gr] += ent;
    dsqb[w] = dsq;
  }
  __syncthreads();

  // ---- coalesced X^T write-back: 8 threads x ushort2 = 32B run per column ----
  if (t < CPAD * 8) {
    int c = t >> 3, jl = (t & 7) * 2;
    ushort2 v = *(const ushort2*)&xbuf[c * 18 + jl];
    *(ushort2*)(XTw + (size_t)c * BROWS + NLAB + r0 + jl) = v;
  }
  if (t == 0) {
    float ds = 0.f;
#pragma unroll
    for (int i = 0; i < 16; i++) ds += dsqb[i];
    atomicAdd(&errsq[it], ds);
  }
}

__global__ __launch_bounds__(256) void k_final(const float* __restrict__ hist,
                                               float* __restrict__ out) {
  int i = blockIdx.x * 256 + threadIdx.x;
  float yt = (i < NLAB) ? 0.0f : hist[i - NLAB] * (1.0f / 30.0f);
  out[BROWS + i] = yt;
  out[2 * BROWS + i] = (i < NLAB) ? 1.0f : 0.0f;
}

// ---------------------------------------------------------------------------
extern "C" void kernel_launch(void* const* d_in, const int* in_sizes, int n_in,
                              void* d_out, int out_size, void* d_ws, size_t ws_size,
                              hipStream_t stream) {
  const float* emb    = (const float*)d_in[1];
  const int*   labels = (const int*)d_in[2];
  const float* W1 = (const float*)d_in[3];
  const float* b1 = (const float*)d_in[4];
  const float* W2 = (const float*)d_in[5];
  const float* b2 = (const float*)d_in[6];
  const float* W3 = (const float*)d_in[7];
  const float* b3 = (const float*)d_in[8];
  const float* Wc = (const float*)d_in[9];
  const float* bc = (const float*)d_in[10];
  float* out = (float*)d_out;

  char* ws = (char*)d_ws;
  ushort* S    = (ushort*)(ws + OFF_S);
  ushort* Au   = (ushort*)(ws + OFF_AU);
  ushort* Eb   = (ushort*)(ws + OFF_EB);
  ushort* XT0  = (ushort*)(ws + OFF_XT0);
  ushort* XT1  = (ushort*)(ws + OFF_XT1);
  float*  Xu   = (float*)(ws + OFF_XU);
  float*  Plab = (float*)(ws + OFF_PL);
  float*  hist = (float*)(ws + OFF_HIST);
  float*  errs = (float*)(ws + OFF_ERR);
  double* ms   = (double*)(ws + OFF_MS);
  float*  rn   = (float*)(ws + OFF_RN);

  // zero hist + errsq + mean accumulator
  hipMemsetAsync(ws + OFF_HIST, 0, MEMSET_LEN, stream);

  k_prep<<<BROWS, 64, 0, stream>>>(emb, Eb, rn);
  k_mlp<<<BROWS / 4, 256, 0, stream>>>(emb, W1, b1, W2, b2, W3, b3, Wc, bc, out);

  { dim3 g(BROWS / 128, BROWS / 128); k_simM<<<g, 256, 0, stream>>>(Eb, rn, S, ms); }

  // overlay init (Eb dead now)
  { dim3 g(BROWS / 256, CPAD); k_initX<<<g, 256, 0, stream>>>(XT0, XT1, Xu, labels); }

  // k_iter needs 123 KB dynamic LDS (> 64 KB default cap)
  (void)hipFuncSetAttribute((const void*)k_iter,
                            hipFuncAttributeMaxDynamicSharedMemorySize, (int)ITER_DLDS);
  for (int it = 0; it < MAXIT; it++) {
    const ushort* XTr = (it & 1) ? XT1 : XT0;
    ushort*       XTw = (it & 1) ? XT0 : XT1;
    k_iter<<<NUNL / 16, 1024, ITER_DLDS, stream>>>(S, Au, XTr, XTw, Xu, Plab, hist, errs, ms, it);
  }

  k_final<<<BROWS / 256, 256, 0, stream>>>(hist, out);
}